// Round 1
// baseline (37.877 us; speedup 1.0000x reference)
//
#include <hip/hip_runtime.h>

#define RS2 0.70710678118654752440f

// ---------------------------------------------------------------------------
// Prep kernel: fold weights into per-pair gate constants (10 floats per pair).
// Per pair (c,t), weights w0..w4:
//  stage1 diag  = RZ(w0) then CRZ(w1): phase e^{i*st*(w0 + cb*w1)/2}, st=+1 if
//                 target bit==1 else -1  -> store cos/sin of w0/2 and (w0+w1)/2
//  stage2 butterfly = RY(w2), CX, RY(w3):
//                 control=0: RY(w2+w3) = [[c0,-s0],[s0,c0]], sigma=(w2+w3)/2
//                 control=1: RY(w3)@X@RY(w2) = [[sd,cd],[cd,-sd]], delta=(w2-w3)/2
//  stage3 diag  = CRZ(w4): cb? e^{i*st*w4/2} : 1  -> store cos/sin of w4/2
// ---------------------------------------------------------------------------
__global__ void qnn_prep(const float* __restrict__ w, float* __restrict__ ws) {
  int j = threadIdx.x;
  if (j >= 9) return;
  const float* wp = w + j * 5;
  float w0 = wp[0], w1 = wp[1], w2 = wp[2], w3 = wp[3], w4 = wp[4];
  float* o = ws + j * 16;
  float cB, sB, cA, sA, c0, s0, cd, sd, c4, s4;
  __sincosf(0.5f * w0, &sB, &cB);
  __sincosf(0.5f * (w0 + w1), &sA, &cA);
  __sincosf(0.5f * (w2 + w3), &s0, &c0);
  __sincosf(0.5f * (w2 - w3), &sd, &cd);
  __sincosf(0.5f * w4, &s4, &c4);
  o[0] = cB; o[1] = sB; o[2] = cA; o[3] = sA;
  o[4] = c0; o[5] = s0; o[6] = cd; o[7] = sd;
  o[8] = c4; o[9] = s4;
}

// Amplitude index a = r*64 + lane. Qubit q <-> bit (7-q) of a.
// q=0 -> r bit1; q=1 -> r bit0; q>=2 -> lane bit (7-q).
template<int Q>
__device__ __forceinline__ int bitq(int lane, int r) {
  if constexpr (Q == 0) return (r >> 1) & 1;
  else if constexpr (Q == 1) return r & 1;
  else return (lane >> (7 - Q)) & 1;
}

template<int C, int T>
__device__ __forceinline__ void apply_pair(float re[4], float im[4], int lane,
                                           const float* __restrict__ o) {
  const float cB = o[0], sB = o[1], cA = o[2], sA = o[3];
  const float c0 = o[4], s0 = o[5], cd = o[6], sd = o[7];
  const float c4 = o[8], s4 = o[9];

  // ---- stage 1: diagonal RZ(w0) + CRZ(w1)
#pragma unroll
  for (int r = 0; r < 4; ++r) {
    int cb = bitq<C>(lane, r), tb = bitq<T>(lane, r);
    float pc = cb ? cA : cB;
    float ps = cb ? sA : sB;
    ps = tb ? ps : -ps;
    float x = re[r], y = im[r];
    re[r] = x * pc - y * ps;
    im[r] = x * ps + y * pc;
  }

  // ---- stage 2: RY(w2), CX, RY(w3) as one real butterfly on target
  if constexpr (T >= 2) {
    constexpr int MASK = 1 << (7 - T);
#pragma unroll
    for (int r = 0; r < 4; ++r) {
      int cb = bitq<C>(lane, r);
      int tb = bitq<T>(lane, r);
      float ox = __shfl_xor(re[r], MASK, 64);
      float oy = __shfl_xor(im[r], MASK, 64);
      // me-coefficient X, partner-coefficient Y
      float X = cb ? (tb ? -sd : sd) : c0;
      float Y = cb ? cd : (tb ? s0 : -s0);
      re[r] = X * re[r] + Y * ox;
      im[r] = X * im[r] + Y * oy;
    }
  } else {
    // target lives in the register index: in-register butterflies
    constexpr int step = (T == 1) ? 1 : 2;
#pragma unroll
    for (int p = 0; p < 2; ++p) {
      int rA = (T == 1) ? (p * 2) : p;  // target bit 0
      int rB = rA + step;               // target bit 1
      int cb = bitq<C>(lane, rA);       // control differs from target -> same for rA,rB
      float m00 = cb ? sd : c0;
      float m01 = cb ? cd : -s0;
      float m10 = cb ? cd : s0;
      float m11 = cb ? -sd : c0;
      float a0x = re[rA], a0y = im[rA], a1x = re[rB], a1y = im[rB];
      re[rA] = m00 * a0x + m01 * a1x;
      im[rA] = m00 * a0y + m01 * a1y;
      re[rB] = m10 * a0x + m11 * a1x;
      im[rB] = m10 * a0y + m11 * a1y;
    }
  }

  // ---- stage 3: diagonal CRZ(w4)
#pragma unroll
  for (int r = 0; r < 4; ++r) {
    int cb = bitq<C>(lane, r), tb = bitq<T>(lane, r);
    float t1 = tb ? s4 : -s4;
    float ps = cb ? t1 : 0.0f;
    float pc = cb ? c4 : 1.0f;
    float x = re[r], y = im[r];
    re[r] = x * pc - y * ps;
    im[r] = x * ps + y * pc;
  }
}

__global__ __launch_bounds__(256) void qnn_main(const float* __restrict__ in,
                                                const float* __restrict__ ws,
                                                float* __restrict__ out) {
  const int wid = threadIdx.x >> 6;
  const int lane = threadIdx.x & 63;
  const int b = blockIdx.x * 4 + wid;

  // ---- load this sample's 8 angles (broadcast within the wave)
  const float4* ip = (const float4*)(in + b * 8);
  float4 A = ip[0], Bv = ip[1];
  float xs[8] = {A.x, A.y, A.z, A.w, Bv.x, Bv.y, Bv.z, Bv.w};

  // ---- embedding: |psi> = prod_q (RY(x_q) H)|0> -> product state, all real
  float v0[8], v1[8];
#pragma unroll
  for (int q = 0; q < 8; ++q) {
    float s, c;
    __sincosf(0.5f * xs[q], &s, &c);
    v0[q] = (c - s) * RS2;
    v1[q] = (c + s) * RS2;
  }
  float prod = 1.0f;
#pragma unroll
  for (int q = 2; q < 8; ++q) {
    int bit = (lane >> (7 - q)) & 1;
    prod *= bit ? v1[q] : v0[q];
  }
  float re[4], im[4];
#pragma unroll
  for (int r = 0; r < 4; ++r) {
    re[r] = prod * ((r & 1) ? v1[1] : v0[1]) * (((r >> 1) & 1) ? v1[0] : v0[0]);
    im[r] = 0.0f;
  }

  // ---- entangling layer: pairs exactly as in the reference
  apply_pair<0, 1>(re, im, lane, ws + 0 * 16);
  apply_pair<1, 2>(re, im, lane, ws + 1 * 16);
  apply_pair<2, 3>(re, im, lane, ws + 2 * 16);
  apply_pair<3, 0>(re, im, lane, ws + 3 * 16);
  apply_pair<3, 4>(re, im, lane, ws + 4 * 16);
  apply_pair<4, 5>(re, im, lane, ws + 5 * 16);
  apply_pair<5, 6>(re, im, lane, ws + 6 * 16);
  apply_pair<6, 7>(re, im, lane, ws + 7 * 16);
  apply_pair<7, 3>(re, im, lane, ws + 8 * 16);

  // ---- probs over wires 3..7: out index = a & 31; sum over r and lane bit 5
  float loc = 0.0f;
#pragma unroll
  for (int r = 0; r < 4; ++r) loc += re[r] * re[r] + im[r] * im[r];
  loc += __shfl_xor(loc, 32, 64);
  if (lane < 32) out[b * 32 + lane] = loc;
}

extern "C" void kernel_launch(void* const* d_in, const int* in_sizes, int n_in,
                              void* d_out, int out_size, void* d_ws, size_t ws_size,
                              hipStream_t stream) {
  const float* inputs = (const float*)d_in[0];   // (B, 8) f32
  const float* weights = (const float*)d_in[1];  // (1, 45) f32
  float* out = (float*)d_out;                    // (B, 32) f32
  float* ws = (float*)d_ws;                      // >= 9*16*4 = 576 bytes
  const int B = in_sizes[0] / 8;

  hipLaunchKernelGGL(qnn_prep, dim3(1), dim3(64), 0, stream, weights, ws);
  hipLaunchKernelGGL(qnn_main, dim3(B / 4), dim3(256), 0, stream, inputs, ws, out);
}

// Round 2
// 34.304 us; speedup vs baseline: 1.1042x; 1.1042x over previous
//
#include <hip/hip_runtime.h>

typedef float f32x2 __attribute__((ext_vector_type(2)));
#define RS2 0.70710678118654752440f

// ---------------------------------------------------------------------------
// Prep: per pair (c,t) with weights w0..w4, store 10 gate constants:
//   cB,sB = cos/sin(w0/2)        cA,sA = cos/sin((w0+w1)/2)   (D1 diag)
//   c0,s0 = cos/sin((w2+w3)/2)   cd,sd = cos/sin((w2-w3)/2)   (RY,CX,RY bfly)
//   c4,s4 = cos/sin(w4/2)                                     (D3 diag)
// ---------------------------------------------------------------------------
__global__ void qnn_prep(const float* __restrict__ w, float* __restrict__ ws) {
  int j = threadIdx.x;
  if (j >= 9) return;
  const float* wp = w + j * 5;
  float w0 = wp[0], w1 = wp[1], w2 = wp[2], w3 = wp[3], w4 = wp[4];
  float* o = ws + j * 16;
  float cB, sB, cA, sA, c0, s0, cd, sd, c4, s4;
  __sincosf(0.5f * w0, &sB, &cB);
  __sincosf(0.5f * (w0 + w1), &sA, &cA);
  __sincosf(0.5f * (w2 + w3), &s0, &c0);
  __sincosf(0.5f * (w2 - w3), &sd, &cd);
  __sincosf(0.5f * w4, &s4, &c4);
  o[0]=cB; o[1]=sB; o[2]=cA; o[3]=sA; o[4]=c0; o[5]=s0;
  o[6]=cd; o[7]=sd; o[8]=c4; o[9]=s4;
}

struct PC { float cB,sB,cA,sA,c0,s0,cd,sd,c4,s4; };
__device__ __forceinline__ PC loadpc(const float* __restrict__ o) {
  PC c; c.cB=o[0]; c.sB=o[1]; c.cA=o[2]; c.sA=o[3]; c.c0=o[4]; c.s0=o[5];
  c.cd=o[6]; c.sd=o[7]; c.c4=o[8]; c.s4=o[9]; return c;
}

__device__ __forceinline__ f32x2 swap2(f32x2 v) { return (f32x2){v.y, v.x}; }

template<int CTRL>
__device__ __forceinline__ f32x2 dpp2(f32x2 v) {
  int x = __builtin_amdgcn_mov_dpp(__float_as_int(v.x), CTRL, 0xf, 0xf, true);
  int y = __builtin_amdgcn_mov_dpp(__float_as_int(v.y), CTRL, 0xf, 0xf, true);
  return (f32x2){__int_as_float(x), __int_as_float(y)};
}
template<int OFF>
__device__ __forceinline__ f32x2 swz2(f32x2 v) {
  int x = __builtin_amdgcn_ds_swizzle(__float_as_int(v.x), OFF);
  int y = __builtin_amdgcn_ds_swizzle(__float_as_int(v.y), OFF);
  return (f32x2){__int_as_float(x), __int_as_float(y)};
}
__device__ __forceinline__ f32x2 sh32_2(f32x2 v) {
  return (f32x2){__shfl_xor(v.x, 32, 64), __shfl_xor(v.y, 32, 64)};
}

// complex phase multiply per packed amplitude pair
__device__ __forceinline__ void diag(f32x2& R, f32x2& I, f32x2 zr, f32x2 zi) {
  f32x2 r = zr * R - zi * I;
  I = zi * R + zr * I;
  R = r;
}

// butterfly: state' = X*state + Y*partner, partner via SHUF
#define BFLY(SHUF, X, Y) do { \
    f32x2 RoA = SHUF(RA), IoA = SHUF(IA), RoB = SHUF(RB), IoB = SHUF(IB); \
    RA = (X)*RA + (Y)*RoA; IA = (X)*IA + (Y)*IoA; \
    RB = (X)*RB + (Y)*RoB; IB = (X)*IB + (Y)*IoB; \
  } while (0)

// Amplitude layout: a = r*64 + lane, r = (q0<<1)|q1.
// Group A = {r0,r1} (q0=0), B = {r2,r3} (q0=1); component .x: q1=0, .y: q1=1.
// Lane bits: q2..q7 = lane bits 5..0.
__global__ __launch_bounds__(256) void qnn_main(const float* __restrict__ in,
                                                const float* __restrict__ ws,
                                                float* __restrict__ out) {
  const int wid = threadIdx.x >> 6;
  const int lane = threadIdx.x & 63;
  const int b = blockIdx.x * 4 + wid;
  const int q2 = (lane >> 5) & 1, q3 = (lane >> 4) & 1, q4 = (lane >> 3) & 1,
            q5 = (lane >> 2) & 1, q6 = (lane >> 1) & 1, q7 = lane & 1;

  const float4* ip = (const float4*)(in + b * 8);
  float4 A4 = ip[0], B4 = ip[1];
  float xs[8] = {A4.x, A4.y, A4.z, A4.w, B4.x, B4.y, B4.z, B4.w};

  // embedding: product state, all real
  float v0[8], v1[8];
#pragma unroll
  for (int q = 0; q < 8; ++q) {
    float s, c;
    __sincosf(0.5f * xs[q], &s, &c);
    v0[q] = (c - s) * RS2;
    v1[q] = (c + s) * RS2;
  }
  float prod = (q2 ? v1[2] : v0[2]) * (q3 ? v1[3] : v0[3]);
  prod *= (q4 ? v1[4] : v0[4]) * (q5 ? v1[5] : v0[5]);
  prod *= (q6 ? v1[6] : v0[6]) * (q7 ? v1[7] : v0[7]);
  float pA = prod * v0[0], pB = prod * v1[0];
  f32x2 vq1 = {v0[1], v1[1]};
  f32x2 bA = pA * vq1, bB = pB * vq1;

  // ---- G0 = D1 of pair0 (c=q0,t=q1) on real state
  PC P0 = loadpc(ws + 0);
  f32x2 RA = bA * P0.cB, IA = bA * (f32x2){-P0.sB, P0.sB};
  f32x2 RB = bB * P0.cA, IB = bB * (f32x2){-P0.sA, P0.sA};

  // ---- B0: target q1 (component swap), control q0 (group)
  {
    f32x2 dgA = {P0.c0, P0.c0}, offA = {-P0.s0, P0.s0};
    f32x2 dgB = {P0.sd, -P0.sd}, offB = {P0.cd, P0.cd};
    f32x2 nRA = dgA*RA + offA*swap2(RA);
    f32x2 nIA = dgA*IA + offA*swap2(IA);
    f32x2 nRB = dgB*RB + offB*swap2(RB);
    f32x2 nIB = dgB*IB + offB*swap2(IB);
    RA = nRA; IA = nIA; RB = nRB; IB = nIB;
  }

  // ---- G1 = D3_0(q0,q1) * D1_1(q1,q2)
  PC P1 = loadpc(ws + 16);
  {
    float sg = q2 ? 1.f : -1.f;
    f32x2 zr = {P1.cB, P1.cA};
    f32x2 zi = {sg * P1.sB, sg * P1.sA};
    diag(RA, IA, zr, zi);                         // A: d3 = 1
    f32x2 d3r = {P0.c4, P0.c4}, d3i = {-P0.s4, P0.s4};
    f32x2 zrB = d3r*zr - d3i*zi;
    f32x2 ziB = d3r*zi + d3i*zr;
    diag(RB, IB, zrB, ziB);
  }
  // ---- B1: target q2 (mask 32), control q1 (component)
  {
    f32x2 X = {P1.c0, q2 ? -P1.sd : P1.sd};
    f32x2 Y = {q2 ? P1.s0 : -P1.s0, P1.cd};
    BFLY(sh32_2, X, Y);
  }
  // ---- G2 = D3_1(q1,q2) * D1_2(q2,q3)
  PC P2 = loadpc(ws + 32);
  {
    float wr = q2 ? P2.cA : P2.cB;
    float wi = (q3 ? 1.f : -1.f) * (q2 ? P2.sA : P2.sB);
    float ur = P1.c4, ui = q2 ? P1.s4 : -P1.s4;   // d3_1 hits component y only
    f32x2 zr = {wr, ur*wr - ui*wi};
    f32x2 zi = {wi, ur*wi + ui*wr};
    diag(RA, IA, zr, zi);
    diag(RB, IB, zr, zi);
  }
  // ---- B2: target q3 (mask 16), control q2
  {
    float X = q2 ? (q3 ? -P2.sd : P2.sd) : P2.c0;
    float Y = q2 ? P2.cd : (q3 ? P2.s0 : -P2.s0);
    BFLY(swz2<0x401F>, X, Y);
  }
  // ---- G3 = D3_2(q2,q3) * D1_3(q3, q0=group)
  PC P3 = loadpc(ws + 48);
  {
    float ur = q2 ? P2.c4 : 1.f;
    float ui = q2 ? (q3 ? P2.s4 : -P2.s4) : 0.f;
    float dr = q3 ? P3.cA : P3.cB;
    float di = q3 ? P3.sA : P3.sB;                // sign: A -, B +
    float zAr = ur*dr + ui*di, zAi = ui*dr - ur*di;
    float zBr = ur*dr - ui*di, zBi = ui*dr + ur*di;
    diag(RA, IA, (f32x2){zAr, zAr}, (f32x2){zAi, zAi});
    diag(RB, IB, (f32x2){zBr, zBr}, (f32x2){zBi, zBi});
  }
  // ---- B3: target q0 (group mix), control q3
  {
    float m00 = q3 ? P3.sd : P3.c0, m01 = q3 ? P3.cd : -P3.s0;
    float m10 = q3 ? P3.cd : P3.s0, m11 = q3 ? -P3.sd : P3.c0;
    f32x2 nRA = m00*RA + m01*RB, nIA = m00*IA + m01*IB;
    f32x2 nRB = m10*RA + m11*RB, nIB = m10*IA + m11*IB;
    RA = nRA; IA = nIA; RB = nRB; IB = nIB;
  }
  // ---- G4 = D3_3(q3, q0=group) * D1_4(q3,q4)
  PC P4 = loadpc(ws + 64);
  {
    float ar = q3 ? P3.c4 : 1.f;
    float ai = q3 ? P3.s4 : 0.f;                  // group A: -ai, B: +ai
    float wr = q3 ? P4.cA : P4.cB;
    float wi = (q4 ? 1.f : -1.f) * (q3 ? P4.sA : P4.sB);
    float zAr = ar*wr + ai*wi, zAi = ar*wi - ai*wr;
    float zBr = ar*wr - ai*wi, zBi = ar*wi + ai*wr;
    diag(RA, IA, (f32x2){zAr, zAr}, (f32x2){zAi, zAi});
    diag(RB, IB, (f32x2){zBr, zBr}, (f32x2){zBi, zBi});
  }
  // ---- B4: target q4 (mask 8 = DPP row_ror:8), control q3
  {
    float X = q3 ? (q4 ? -P4.sd : P4.sd) : P4.c0;
    float Y = q3 ? P4.cd : (q4 ? P4.s0 : -P4.s0);
    BFLY(dpp2<0x128>, X, Y);
  }
  // ---- G5 = D3_4(q3,q4) * D1_5(q4,q5)
  PC P5 = loadpc(ws + 80);
  {
    float ur = q3 ? P4.c4 : 1.f;
    float ui = q3 ? (q4 ? P4.s4 : -P4.s4) : 0.f;
    float wr = q4 ? P5.cA : P5.cB;
    float wi = (q5 ? 1.f : -1.f) * (q4 ? P5.sA : P5.sB);
    float zr = ur*wr - ui*wi, zi = ur*wi + ui*wr;
    diag(RA, IA, (f32x2){zr, zr}, (f32x2){zi, zi});
    diag(RB, IB, (f32x2){zr, zr}, (f32x2){zi, zi});
  }
  // ---- B5: target q5 (mask 4 = ds_swizzle xor4), control q4
  {
    float X = q4 ? (q5 ? -P5.sd : P5.sd) : P5.c0;
    float Y = q4 ? P5.cd : (q5 ? P5.s0 : -P5.s0);
    BFLY(swz2<0x101F>, X, Y);
  }
  // ---- G6 = D3_5(q4,q5) * D1_6(q5,q6)
  PC P6 = loadpc(ws + 96);
  {
    float ur = q4 ? P5.c4 : 1.f;
    float ui = q4 ? (q5 ? P5.s4 : -P5.s4) : 0.f;
    float wr = q5 ? P6.cA : P6.cB;
    float wi = (q6 ? 1.f : -1.f) * (q5 ? P6.sA : P6.sB);
    float zr = ur*wr - ui*wi, zi = ur*wi + ui*wr;
    diag(RA, IA, (f32x2){zr, zr}, (f32x2){zi, zi});
    diag(RB, IB, (f32x2){zr, zr}, (f32x2){zi, zi});
  }
  // ---- B6: target q6 (mask 2 = DPP quad_perm [2,3,0,1]), control q5
  {
    float X = q5 ? (q6 ? -P6.sd : P6.sd) : P6.c0;
    float Y = q5 ? P6.cd : (q6 ? P6.s0 : -P6.s0);
    BFLY(dpp2<0x4E>, X, Y);
  }
  // ---- G7 = D3_6(q5,q6) * D1_7(q6,q7)
  PC P7 = loadpc(ws + 112);
  {
    float ur = q5 ? P6.c4 : 1.f;
    float ui = q5 ? (q6 ? P6.s4 : -P6.s4) : 0.f;
    float wr = q6 ? P7.cA : P7.cB;
    float wi = (q7 ? 1.f : -1.f) * (q6 ? P7.sA : P7.sB);
    float zr = ur*wr - ui*wi, zi = ur*wi + ui*wr;
    diag(RA, IA, (f32x2){zr, zr}, (f32x2){zi, zi});
    diag(RB, IB, (f32x2){zr, zr}, (f32x2){zi, zi});
  }
  // ---- B7: target q7 (mask 1 = DPP quad_perm [1,0,3,2]), control q6
  {
    float X = q6 ? (q7 ? -P7.sd : P7.sd) : P7.c0;
    float Y = q6 ? P7.cd : (q7 ? P7.s0 : -P7.s0);
    BFLY(dpp2<0xB1>, X, Y);
  }
  // ---- G8 = D3_7(q6,q7) * D1_8(q7,q3)
  PC P8 = loadpc(ws + 128);
  {
    float ur = q6 ? P7.c4 : 1.f;
    float ui = q6 ? (q7 ? P7.s4 : -P7.s4) : 0.f;
    float wr = q7 ? P8.cA : P8.cB;
    float wi = (q3 ? 1.f : -1.f) * (q7 ? P8.sA : P8.sB);
    float zr = ur*wr - ui*wi, zi = ur*wi + ui*wr;
    diag(RA, IA, (f32x2){zr, zr}, (f32x2){zi, zi});
    diag(RB, IB, (f32x2){zr, zr}, (f32x2){zi, zi});
  }
  // ---- B8: target q3 (mask 16), control q7.  Final D3 dropped (pure phase).
  {
    float X = q7 ? (q3 ? -P8.sd : P8.sd) : P8.c0;
    float Y = q7 ? P8.cd : (q3 ? P8.s0 : -P8.s0);
    BFLY(swz2<0x401F>, X, Y);
  }

  // probs over wires 3..7: out idx = lane&31; sum over r and lane bit of q2
  f32x2 acc = RA*RA + IA*IA + RB*RB + IB*IB;
  float loc = acc.x + acc.y;
  loc += __shfl_xor(loc, 32, 64);
  if (lane < 32) out[b * 32 + lane] = loc;
}

extern "C" void kernel_launch(void* const* d_in, const int* in_sizes, int n_in,
                              void* d_out, int out_size, void* d_ws, size_t ws_size,
                              hipStream_t stream) {
  const float* inputs = (const float*)d_in[0];   // (B, 8) f32
  const float* weights = (const float*)d_in[1];  // (1, 45) f32
  float* out = (float*)d_out;                    // (B, 32) f32
  float* ws = (float*)d_ws;                      // 9*16*4 = 576 bytes used
  const int B = in_sizes[0] / 8;

  hipLaunchKernelGGL(qnn_prep, dim3(1), dim3(64), 0, stream, weights, ws);
  hipLaunchKernelGGL(qnn_main, dim3(B / 4), dim3(256), 0, stream, inputs, ws, out);
}

// Round 3
// 31.949 us; speedup vs baseline: 1.1856x; 1.0737x over previous
//
#include <hip/hip_runtime.h>

typedef float f32x2 __attribute__((ext_vector_type(2)));
#define RS2 0.70710678118654752440f
#define PI4 0.78539816339744830962f

// ---------------------------------------------------------------------------
// Prep: per pair (c,t) with weights w0..w4, 10 gate constants at ws[j*10+k]:
//   cB,sB = cos/sin(w0/2)        cA,sA = cos/sin((w0+w1)/2)   (D1 diag)
//   c0,s0 = cos/sin((w2+w3)/2)   cd,sd = cos/sin((w2-w3)/2)   (RY,CX,RY bfly)
//   c4,s4 = cos/sin(w4/2)                                     (D3 diag)
// ---------------------------------------------------------------------------
__global__ void qnn_prep(const float* __restrict__ w, float* __restrict__ ws) {
  int j = threadIdx.x;
  if (j >= 9) return;
  const float* wp = w + j * 5;
  float w0 = wp[0], w1 = wp[1], w2 = wp[2], w3 = wp[3], w4 = wp[4];
  float* o = ws + j * 10;
  float cB, sB, cA, sA, c0, s0, cd, sd, c4, s4;
  __sincosf(0.5f * w0, &sB, &cB);
  __sincosf(0.5f * (w0 + w1), &sA, &cA);
  __sincosf(0.5f * (w2 + w3), &s0, &c0);
  __sincosf(0.5f * (w2 - w3), &sd, &cd);
  __sincosf(0.5f * w4, &s4, &c4);
  o[0]=cB; o[1]=sB; o[2]=cA; o[3]=sA; o[4]=c0; o[5]=s0;
  o[6]=cd; o[7]=sd; o[8]=c4; o[9]=s4;
}

// Extract wave-uniform constant IDX from the lane-distributed pair (t0,t1).
template<int IDX>
__device__ __forceinline__ float getc(float t0, float t1) {
  float src = (IDX < 64) ? t0 : t1;
  return __int_as_float(__builtin_amdgcn_readlane(__float_as_int(src), IDX & 63));
}

struct PC { float cB,sB,cA,sA,c0,s0,cd,sd,c4,s4; };
template<int J>
__device__ __forceinline__ PC loadpc(float t0, float t1) {
  PC c;
  c.cB = getc<J*10+0>(t0,t1); c.sB = getc<J*10+1>(t0,t1);
  c.cA = getc<J*10+2>(t0,t1); c.sA = getc<J*10+3>(t0,t1);
  c.c0 = getc<J*10+4>(t0,t1); c.s0 = getc<J*10+5>(t0,t1);
  c.cd = getc<J*10+6>(t0,t1); c.sd = getc<J*10+7>(t0,t1);
  c.c4 = getc<J*10+8>(t0,t1); c.s4 = getc<J*10+9>(t0,t1);
  return c;
}

__device__ __forceinline__ f32x2 swap2(f32x2 v) { return (f32x2){v.y, v.x}; }

template<int CTRL>
__device__ __forceinline__ f32x2 dpp2(f32x2 v) {
  int x = __builtin_amdgcn_mov_dpp(__float_as_int(v.x), CTRL, 0xf, 0xf, true);
  int y = __builtin_amdgcn_mov_dpp(__float_as_int(v.y), CTRL, 0xf, 0xf, true);
  return (f32x2){__int_as_float(x), __int_as_float(y)};
}
template<int OFF>
__device__ __forceinline__ f32x2 swz2(f32x2 v) {
  int x = __builtin_amdgcn_ds_swizzle(__float_as_int(v.x), OFF);
  int y = __builtin_amdgcn_ds_swizzle(__float_as_int(v.y), OFF);
  return (f32x2){__int_as_float(x), __int_as_float(y)};
}
__device__ __forceinline__ f32x2 sh32_2(f32x2 v) {
  return (f32x2){__shfl_xor(v.x, 32, 64), __shfl_xor(v.y, 32, 64)};
}

__device__ __forceinline__ void diag(f32x2& R, f32x2& I, f32x2 zr, f32x2 zi) {
  f32x2 r = zr * R - zi * I;
  I = zi * R + zr * I;
  R = r;
}

// butterfly update of sample s with coefficients X (me), Y (partner)
#define BFLY_S(SHUF, s, X, Y) do { \
    f32x2 RoA = SHUF(RA[s]), IoA = SHUF(IA[s]), RoB = SHUF(RB[s]), IoB = SHUF(IB[s]); \
    RA[s] = (X)*RA[s] + (Y)*RoA; IA[s] = (X)*IA[s] + (Y)*IoA; \
    RB[s] = (X)*RB[s] + (Y)*RoB; IB[s] = (X)*IB[s] + (Y)*IoB; \
  } while (0)

// Amplitude layout per sample: a = r*64 + lane, r = (q0<<1)|q1.
// Group A (q0=0) / B (q0=1); component .x: q1=0, .y: q1=1.
// Lane bits: q2..q7 = lane bits 5..0. Two samples per wave.
__global__ __launch_bounds__(256, 8) void qnn_main(const float* __restrict__ in,
                                                   const float* __restrict__ ws,
                                                   float* __restrict__ out) {
  const int wid = threadIdx.x >> 6;
  const int lane = threadIdx.x & 63;
  const int wv = blockIdx.x * 4 + wid;
  const int b0 = wv * 2;
  const int q2 = (lane >> 5) & 1, q3 = (lane >> 4) & 1, q4 = (lane >> 3) & 1,
            q5 = (lane >> 2) & 1, q6 = (lane >> 1) & 1, q7 = lane & 1;

  // lane-distributed constant block (90 floats; reads to ws[127] stay in ws)
  float t0 = ws[lane];
  float t1 = ws[64 + lane];

  // ---- embedding for both samples: product state, all real
  f32x2 bA[2], bB[2];
#pragma unroll
  for (int s = 0; s < 2; ++s) {
    const float4* ip = (const float4*)(in + (b0 + s) * 8);
    float4 A4 = ip[0], B4 = ip[1];
    float xs[8] = {A4.x, A4.y, A4.z, A4.w, B4.x, B4.y, B4.z, B4.w};
    float vc[8], vs[8];
#pragma unroll
    for (int q = 0; q < 8; ++q)
      __sincosf(0.5f * xs[q] + PI4, &vs[q], &vc[q]);  // v0=cos, v1=sin
    float prod = (q2 ? vs[2] : vc[2]) * (q3 ? vs[3] : vc[3]);
    prod *= (q4 ? vs[4] : vc[4]) * (q5 ? vs[5] : vc[5]);
    prod *= (q6 ? vs[6] : vc[6]) * (q7 ? vs[7] : vc[7]);
    f32x2 vq1 = {vc[1], vs[1]};
    bA[s] = (prod * vc[0]) * vq1;
    bB[s] = (prod * vs[0]) * vq1;
  }

  f32x2 RA[2], IA[2], RB[2], IB[2];

  // ---- G0 = D1 of pair0 (c=q0,t=q1) on real state; B0: target q1, ctrl q0
  PC P0 = loadpc<0>(t0, t1);
  {
    f32x2 mB = {-P0.sB, P0.sB}, mA = {-P0.sA, P0.sA};
    f32x2 offA = {-P0.s0, P0.s0}, dgB = {P0.sd, -P0.sd};
#pragma unroll
    for (int s = 0; s < 2; ++s) {
      f32x2 r0 = bA[s] * P0.cB, i0 = bA[s] * mB;
      f32x2 r1 = bB[s] * P0.cA, i1 = bB[s] * mA;
      RA[s] = P0.c0 * r0 + offA * swap2(r0);
      IA[s] = P0.c0 * i0 + offA * swap2(i0);
      RB[s] = dgB * r1 + P0.cd * swap2(r1);
      IB[s] = dgB * i1 + P0.cd * swap2(i1);
    }
  }

  // ---- G1 = D3_0(q0,q1) * D1_1(q1,q2)
  PC P1 = loadpc<1>(t0, t1);
  {
    float sg = q2 ? 1.f : -1.f;
    f32x2 zr = {P1.cB, P1.cA};
    f32x2 zi = sg * (f32x2){P1.sB, P1.sA};
    f32x2 d3i = {-P0.s4, P0.s4};
    f32x2 zrB = P0.c4 * zr - d3i * zi;
    f32x2 ziB = P0.c4 * zi + d3i * zr;
#pragma unroll
    for (int s = 0; s < 2; ++s) {
      diag(RA[s], IA[s], zr, zi);
      diag(RB[s], IB[s], zrB, ziB);
    }
  }
  // ---- B1: target q2 (mask 32), control q1 (component)
  {
    f32x2 X = {P1.c0, q2 ? -P1.sd : P1.sd};
    f32x2 Y = {q2 ? P1.s0 : -P1.s0, P1.cd};
#pragma unroll
    for (int s = 0; s < 2; ++s) BFLY_S(sh32_2, s, X, Y);
  }

  // ---- G2 = D3_1(q1,q2) * D1_2(q2,q3)
  PC P2 = loadpc<2>(t0, t1);
  {
    float wr = q2 ? P2.cA : P2.cB;
    float wi = (q3 ? 1.f : -1.f) * (q2 ? P2.sA : P2.sB);
    float ur = P1.c4, ui = q2 ? P1.s4 : -P1.s4;  // d3_1 hits component y only
    f32x2 zr = {wr, ur*wr - ui*wi};
    f32x2 zi = {wi, ur*wi + ui*wr};
#pragma unroll
    for (int s = 0; s < 2; ++s) { diag(RA[s],IA[s],zr,zi); diag(RB[s],IB[s],zr,zi); }
  }
  // ---- B2: target q3 (mask 16), control q2
  {
    float X = q2 ? (q3 ? -P2.sd : P2.sd) : P2.c0;
    float Y = q2 ? P2.cd : (q3 ? P2.s0 : -P2.s0);
#pragma unroll
    for (int s = 0; s < 2; ++s) BFLY_S(swz2<0x401F>, s, X, Y);
  }

  // ---- G3 = D3_2(q2,q3) * D1_3(q3, q0=group)
  PC P3 = loadpc<3>(t0, t1);
  {
    float ur = q2 ? P2.c4 : 1.f;
    float ui = q2 ? (q3 ? P2.s4 : -P2.s4) : 0.f;
    float dr = q3 ? P3.cA : P3.cB;
    float di = q3 ? P3.sA : P3.sB;  // sign: group A -, group B +
    float zAr = ur*dr + ui*di, zAi = ui*dr - ur*di;
    float zBr = ur*dr - ui*di, zBi = ui*dr + ur*di;
#pragma unroll
    for (int s = 0; s < 2; ++s) {
      diag(RA[s], IA[s], (f32x2){zAr,zAr}, (f32x2){zAi,zAi});
      diag(RB[s], IB[s], (f32x2){zBr,zBr}, (f32x2){zBi,zBi});
    }
  }
  // ---- B3: target q0 (group mix), control q3
  {
    float m00 = q3 ? P3.sd : P3.c0, m01 = q3 ? P3.cd : -P3.s0;
    float m10 = q3 ? P3.cd : P3.s0, m11 = q3 ? -P3.sd : P3.c0;
#pragma unroll
    for (int s = 0; s < 2; ++s) {
      f32x2 nRA = m00*RA[s] + m01*RB[s], nIA = m00*IA[s] + m01*IB[s];
      f32x2 nRB = m10*RA[s] + m11*RB[s], nIB = m10*IA[s] + m11*IB[s];
      RA[s]=nRA; IA[s]=nIA; RB[s]=nRB; IB[s]=nIB;
    }
  }

  // ---- G4 = D3_3(q3, q0=group) * D1_4(q3,q4)
  PC P4 = loadpc<4>(t0, t1);
  {
    float ar = q3 ? P3.c4 : 1.f;
    float ai = q3 ? P3.s4 : 0.f;  // group A: -ai, B: +ai
    float wr = q3 ? P4.cA : P4.cB;
    float wi = (q4 ? 1.f : -1.f) * (q3 ? P4.sA : P4.sB);
    float zAr = ar*wr + ai*wi, zAi = ar*wi - ai*wr;
    float zBr = ar*wr - ai*wi, zBi = ar*wi + ai*wr;
#pragma unroll
    for (int s = 0; s < 2; ++s) {
      diag(RA[s], IA[s], (f32x2){zAr,zAr}, (f32x2){zAi,zAi});
      diag(RB[s], IB[s], (f32x2){zBr,zBr}, (f32x2){zBi,zBi});
    }
  }
  // ---- B4: target q4 (mask 8 = DPP row_ror:8), control q3
  {
    float X = q3 ? (q4 ? -P4.sd : P4.sd) : P4.c0;
    float Y = q3 ? P4.cd : (q4 ? P4.s0 : -P4.s0);
#pragma unroll
    for (int s = 0; s < 2; ++s) BFLY_S(dpp2<0x128>, s, X, Y);
  }

  // ---- G5 = D3_4(q3,q4) * D1_5(q4,q5)
  PC P5 = loadpc<5>(t0, t1);
  {
    float ur = q3 ? P4.c4 : 1.f;
    float ui = q3 ? (q4 ? P4.s4 : -P4.s4) : 0.f;
    float wr = q4 ? P5.cA : P5.cB;
    float wi = (q5 ? 1.f : -1.f) * (q4 ? P5.sA : P5.sB);
    float zr = ur*wr - ui*wi, zi = ur*wi + ui*wr;
#pragma unroll
    for (int s = 0; s < 2; ++s) {
      diag(RA[s], IA[s], (f32x2){zr,zr}, (f32x2){zi,zi});
      diag(RB[s], IB[s], (f32x2){zr,zr}, (f32x2){zi,zi});
    }
  }
  // ---- B5: target q5 (mask 4 = ds_swizzle xor4), control q4
  {
    float X = q4 ? (q5 ? -P5.sd : P5.sd) : P5.c0;
    float Y = q4 ? P5.cd : (q5 ? P5.s0 : -P5.s0);
#pragma unroll
    for (int s = 0; s < 2; ++s) BFLY_S(swz2<0x101F>, s, X, Y);
  }

  // ---- G6 = D3_5(q4,q5) * D1_6(q5,q6)
  PC P6 = loadpc<6>(t0, t1);
  {
    float ur = q4 ? P5.c4 : 1.f;
    float ui = q4 ? (q5 ? P5.s4 : -P5.s4) : 0.f;
    float wr = q5 ? P6.cA : P6.cB;
    float wi = (q6 ? 1.f : -1.f) * (q5 ? P6.sA : P6.sB);
    float zr = ur*wr - ui*wi, zi = ur*wi + ui*wr;
#pragma unroll
    for (int s = 0; s < 2; ++s) {
      diag(RA[s], IA[s], (f32x2){zr,zr}, (f32x2){zi,zi});
      diag(RB[s], IB[s], (f32x2){zr,zr}, (f32x2){zi,zi});
    }
  }
  // ---- B6: target q6 (mask 2 = DPP quad_perm [2,3,0,1]), control q5
  {
    float X = q5 ? (q6 ? -P6.sd : P6.sd) : P6.c0;
    float Y = q5 ? P6.cd : (q6 ? P6.s0 : -P6.s0);
#pragma unroll
    for (int s = 0; s < 2; ++s) BFLY_S(dpp2<0x4E>, s, X, Y);
  }

  // ---- G7 = D3_6(q5,q6) * D1_7(q6,q7)
  PC P7 = loadpc<7>(t0, t1);
  {
    float ur = q5 ? P6.c4 : 1.f;
    float ui = q5 ? (q6 ? P6.s4 : -P6.s4) : 0.f;
    float wr = q6 ? P7.cA : P7.cB;
    float wi = (q7 ? 1.f : -1.f) * (q6 ? P7.sA : P7.sB);
    float zr = ur*wr - ui*wi, zi = ur*wi + ui*wr;
#pragma unroll
    for (int s = 0; s < 2; ++s) {
      diag(RA[s], IA[s], (f32x2){zr,zr}, (f32x2){zi,zi});
      diag(RB[s], IB[s], (f32x2){zr,zr}, (f32x2){zi,zi});
    }
  }
  // ---- B7: target q7 (mask 1 = DPP quad_perm [1,0,3,2]), control q6
  {
    float X = q6 ? (q7 ? -P7.sd : P7.sd) : P7.c0;
    float Y = q6 ? P7.cd : (q7 ? P7.s0 : -P7.s0);
#pragma unroll
    for (int s = 0; s < 2; ++s) BFLY_S(dpp2<0xB1>, s, X, Y);
  }

  // ---- G8 = D3_7(q6,q7) * D1_8(q7,q3)
  PC P8 = loadpc<8>(t0, t1);
  {
    float ur = q6 ? P7.c4 : 1.f;
    float ui = q6 ? (q7 ? P7.s4 : -P7.s4) : 0.f;
    float wr = q7 ? P8.cA : P8.cB;
    float wi = (q3 ? 1.f : -1.f) * (q7 ? P8.sA : P8.sB);
    float zr = ur*wr - ui*wi, zi = ur*wi + ui*wr;
#pragma unroll
    for (int s = 0; s < 2; ++s) {
      diag(RA[s], IA[s], (f32x2){zr,zr}, (f32x2){zi,zi});
      diag(RB[s], IB[s], (f32x2){zr,zr}, (f32x2){zi,zi});
    }
  }
  // ---- B8: target q3 (mask 16), control q7. Final D3 dropped (pure phase).
  {
    float X = q7 ? (q3 ? -P8.sd : P8.sd) : P8.c0;
    float Y = q7 ? P8.cd : (q3 ? P8.s0 : -P8.s0);
#pragma unroll
    for (int s = 0; s < 2; ++s) BFLY_S(swz2<0x401F>, s, X, Y);
  }

  // ---- probs over wires 3..7; full-wave coalesced store:
  // lanes<32 hold sample b0's 32 probs, lanes>=32 hold sample b1's.
  float loc[2];
#pragma unroll
  for (int s = 0; s < 2; ++s) {
    f32x2 acc = RA[s]*RA[s] + IA[s]*IA[s] + RB[s]*RB[s] + IB[s]*IB[s];
    float l = acc.x + acc.y;
    loc[s] = l + __shfl_xor(l, 32, 64);
  }
  out[wv * 64 + lane] = (lane < 32) ? loc[0] : loc[1];
}

extern "C" void kernel_launch(void* const* d_in, const int* in_sizes, int n_in,
                              void* d_out, int out_size, void* d_ws, size_t ws_size,
                              hipStream_t stream) {
  const float* inputs = (const float*)d_in[0];   // (B, 8) f32
  const float* weights = (const float*)d_in[1];  // (1, 45) f32
  float* out = (float*)d_out;                    // (B, 32) f32
  float* ws = (float*)d_ws;                      // 90 floats used (+pad reads)
  const int B = in_sizes[0] / 8;

  hipLaunchKernelGGL(qnn_prep, dim3(1), dim3(64), 0, stream, weights, ws);
  hipLaunchKernelGGL(qnn_main, dim3(B / 8), dim3(256), 0, stream, inputs, ws, out);
}

// Round 4
// 29.140 us; speedup vs baseline: 1.2998x; 1.0964x over previous
//
#include <hip/hip_runtime.h>

typedef float f32x2 __attribute__((ext_vector_type(2)));

// 1/(4*pi): rev = angle(w)/2 / (2*pi)
#define HALF_INV2PI 0.07957747154594766788f

// ---------------------------------------------------------------------------
// Packed f32 VOP3P helpers (hipcc scalarizes ext_vector f32 math; emit by hand)
// ---------------------------------------------------------------------------
__device__ __forceinline__ f32x2 pk_mul(f32x2 a, f32x2 b) {
  f32x2 d; asm("v_pk_mul_f32 %0, %1, %2" : "=v"(d) : "v"(a), "v"(b)); return d;
}
__device__ __forceinline__ f32x2 pk_fma(f32x2 a, f32x2 b, f32x2 c) {
  f32x2 d; asm("v_pk_fma_f32 %0, %1, %2, %3" : "=v"(d) : "v"(a), "v"(b), "v"(c));
  return d;
}
// a*b - c
__device__ __forceinline__ f32x2 pk_fms(f32x2 a, f32x2 b, f32x2 c) {
  f32x2 d; asm("v_pk_fma_f32 %0, %1, %2, %3 neg_lo:[0,0,1] neg_hi:[0,0,1]"
               : "=v"(d) : "v"(a), "v"(b), "v"(c));
  return d;
}
// a*swap(b) + c   (op_sel picks hi half of src1 for lo result and vice versa)
__device__ __forceinline__ f32x2 pk_fma_sw(f32x2 a, f32x2 b, f32x2 c) {
  f32x2 d; asm("v_pk_fma_f32 %0, %1, %2, %3 op_sel:[0,1,0] op_sel_hi:[1,0,1]"
               : "=v"(d) : "v"(a), "v"(b), "v"(c));
  return d;
}

// hardware sincos: v_sin/v_cos take revolutions
__device__ __forceinline__ void hw_sc(float rev, float& s, float& c) {
  s = __builtin_amdgcn_sinf(rev);
  c = __builtin_amdgcn_cosf(rev);
}

template<int J>
__device__ __forceinline__ float rl(float x) {
  return __int_as_float(__builtin_amdgcn_readlane(__float_as_int(x), J));
}

struct PC { float cB,sB,cA,sA,c0,s0,cd,sd,c4,s4; };
// broadcast pair-J constants out of the lane-parallel registers
template<int J>
__device__ __forceinline__ PC loadpc(float cB,float sB,float cA,float sA,
                                     float c0,float s0,float cd,float sd,
                                     float c4,float s4) {
  PC c;
  c.cB=rl<J>(cB); c.sB=rl<J>(sB); c.cA=rl<J>(cA); c.sA=rl<J>(sA);
  c.c0=rl<J>(c0); c.s0=rl<J>(s0); c.cd=rl<J>(cd); c.sd=rl<J>(sd);
  c.c4=rl<J>(c4); c.s4=rl<J>(s4);
  return c;
}

template<int CTRL>
__device__ __forceinline__ f32x2 dpp2(f32x2 v) {
  int x = __builtin_amdgcn_mov_dpp(__float_as_int(v.x), CTRL, 0xf, 0xf, true);
  int y = __builtin_amdgcn_mov_dpp(__float_as_int(v.y), CTRL, 0xf, 0xf, true);
  return (f32x2){__int_as_float(x), __int_as_float(y)};
}
template<int OFF>
__device__ __forceinline__ f32x2 swz2(f32x2 v) {
  int x = __builtin_amdgcn_ds_swizzle(__float_as_int(v.x), OFF);
  int y = __builtin_amdgcn_ds_swizzle(__float_as_int(v.y), OFF);
  return (f32x2){__int_as_float(x), __int_as_float(y)};
}
__device__ __forceinline__ f32x2 sh32_2(f32x2 v) {
  return (f32x2){__shfl_xor(v.x, 32, 64), __shfl_xor(v.y, 32, 64)};
}

// complex phase multiply (packed over the two q1-components)
__device__ __forceinline__ void diag(f32x2& R, f32x2& I, f32x2 zr, f32x2 zi) {
  f32x2 nR = pk_fms(zr, R, pk_mul(zi, I));
  f32x2 nI = pk_fma(zi, R, pk_mul(zr, I));
  R = nR; I = nI;
}

// butterfly: v' = X*v + Y*shuf(v)
#define BFLY_S(SHUF, s, X, Y) do { \
    f32x2 RoA = SHUF(RA[s]), IoA = SHUF(IA[s]), RoB = SHUF(RB[s]), IoB = SHUF(IB[s]); \
    RA[s] = pk_fma((Y), RoA, pk_mul((X), RA[s])); \
    IA[s] = pk_fma((Y), IoA, pk_mul((X), IA[s])); \
    RB[s] = pk_fma((Y), RoB, pk_mul((X), RB[s])); \
    IB[s] = pk_fma((Y), IoB, pk_mul((X), IB[s])); \
  } while (0)

// ---------------------------------------------------------------------------
// Amplitude layout per sample: group A/B = q0 (register), component .x/.y = q1.
// Lane bits: q2=bit5, q4=bit4, q3=bit3, q5=bit2, q6=bit1, q7=bit0.
// (q3 sits on a DPP-able bit: it is butterflied twice.)
// Two samples per wave.
// ---------------------------------------------------------------------------
__global__ __launch_bounds__(256, 6) void qnn_main(const float* __restrict__ in,
                                                   const float* __restrict__ w,
                                                   float* __restrict__ out) {
  const int wid = threadIdx.x >> 6;
  const int lane = threadIdx.x & 63;
  const int wv = blockIdx.x * 4 + wid;
  const int b0 = wv * 2;
  const int q2 = (lane >> 5) & 1, q4 = (lane >> 4) & 1, q3 = (lane >> 3) & 1,
            q5 = (lane >> 2) & 1, q6 = (lane >> 1) & 1, q7 = lane & 1;

  // ---- in-kernel prep: lane j (j<9) computes pair j's 10 gate constants
  float gcB, gsB, gcA, gsA, gc0, gs0, gcd, gsd, gc4, gs4;
  {
    const int jj = (lane < 9) ? lane : 0;
    const float* wp = w + jj * 5;
    float w0 = wp[0], w1 = wp[1], w2 = wp[2], w3 = wp[3], w4 = wp[4];
    hw_sc(w0 * HALF_INV2PI, gsB, gcB);          // cos/sin(w0/2)
    hw_sc((w0 + w1) * HALF_INV2PI, gsA, gcA);   // cos/sin((w0+w1)/2)
    hw_sc((w2 + w3) * HALF_INV2PI, gs0, gc0);   // cos/sin((w2+w3)/2)
    hw_sc((w2 - w3) * HALF_INV2PI, gsd, gcd);   // cos/sin((w2-w3)/2)
    hw_sc(w4 * HALF_INV2PI, gs4, gc4);          // cos/sin(w4/2)
  }
#define LOADPC(J) loadpc<J>(gcB,gsB,gcA,gsA,gc0,gs0,gcd,gsd,gc4,gs4)

  // ---- embedding for both samples: product state, all real
  // v0 = cos(x/2 + pi/4), v1 = sin(x/2 + pi/4); rev = x*(1/(4pi)) + 0.125
  f32x2 bA[2], bB[2];
#pragma unroll
  for (int s = 0; s < 2; ++s) {
    const float4* ip = (const float4*)(in + (b0 + s) * 8);
    float4 A4 = ip[0], B4 = ip[1];
    float xs[8] = {A4.x, A4.y, A4.z, A4.w, B4.x, B4.y, B4.z, B4.w};
    float vc[8], vs[8];
#pragma unroll
    for (int q = 0; q < 8; ++q)
      hw_sc(__builtin_fmaf(xs[q], HALF_INV2PI, 0.125f), vs[q], vc[q]);
    float prod = (q2 ? vs[2] : vc[2]) * (q3 ? vs[3] : vc[3]);
    prod *= (q4 ? vs[4] : vc[4]) * (q5 ? vs[5] : vc[5]);
    prod *= (q6 ? vs[6] : vc[6]) * (q7 ? vs[7] : vc[7]);
    f32x2 vq1 = {vc[1], vs[1]};
    bA[s] = (prod * vc[0]) * vq1;
    bB[s] = (prod * vs[0]) * vq1;
  }

  f32x2 RA[2], IA[2], RB[2], IB[2];

  // ---- G0 = D1 of pair0 (c=q0,t=q1) on real state; B0: target q1 (comp swap)
  PC P0 = LOADPC(0);
  {
    f32x2 cB2 = {P0.cB, P0.cB}, mB = {-P0.sB, P0.sB};
    f32x2 cA2 = {P0.cA, P0.cA}, mA = {-P0.sA, P0.sA};
    f32x2 cc0 = {P0.c0, P0.c0}, offA = {-P0.s0, P0.s0};
    f32x2 dgB = {P0.sd, -P0.sd}, ccd = {P0.cd, P0.cd};
#pragma unroll
    for (int s = 0; s < 2; ++s) {
      f32x2 r0 = pk_mul(bA[s], cB2), i0 = pk_mul(bA[s], mB);
      f32x2 r1 = pk_mul(bB[s], cA2), i1 = pk_mul(bB[s], mA);
      RA[s] = pk_fma_sw(offA, r0, pk_mul(cc0, r0));
      IA[s] = pk_fma_sw(offA, i0, pk_mul(cc0, i0));
      RB[s] = pk_fma_sw(ccd, r1, pk_mul(dgB, r1));
      IB[s] = pk_fma_sw(ccd, i1, pk_mul(dgB, i1));
    }
  }

  // ---- G1 = D3_0(q0,q1) * D1_1(q1,q2)
  PC P1 = LOADPC(1);
  {
    float sg = q2 ? 1.f : -1.f;
    f32x2 zr = {P1.cB, P1.cA};
    f32x2 zi = {sg * P1.sB, sg * P1.sA};
    f32x2 d3r = {P0.c4, P0.c4}, d3i = {-P0.s4, P0.s4};
    f32x2 zrB = pk_fms(d3r, zr, pk_mul(d3i, zi));
    f32x2 ziB = pk_fma(d3i, zr, pk_mul(d3r, zi));
#pragma unroll
    for (int s = 0; s < 2; ++s) {
      diag(RA[s], IA[s], zr, zi);
      diag(RB[s], IB[s], zrB, ziB);
    }
  }
  // ---- B1: target q2 (bit5 -> xor32), control q1 (component)
  {
    f32x2 X = {P1.c0, q2 ? -P1.sd : P1.sd};
    f32x2 Y = {q2 ? P1.s0 : -P1.s0, P1.cd};
#pragma unroll
    for (int s = 0; s < 2; ++s) BFLY_S(sh32_2, s, X, Y);
  }

  // ---- G2 = D3_1(q1,q2) * D1_2(q2,q3)
  PC P2 = LOADPC(2);
  {
    float wr = q2 ? P2.cA : P2.cB;
    float wi = (q3 ? 1.f : -1.f) * (q2 ? P2.sA : P2.sB);
    float ur = P1.c4, ui = q2 ? P1.s4 : -P1.s4;  // d3_1 hits component y only
    f32x2 zr = {wr, ur*wr - ui*wi};
    f32x2 zi = {wi, ur*wi + ui*wr};
#pragma unroll
    for (int s = 0; s < 2; ++s) { diag(RA[s],IA[s],zr,zi); diag(RB[s],IB[s],zr,zi); }
  }
  // ---- B2: target q3 (bit3 -> xor8 = DPP row_ror:8), control q2
  {
    float X = q2 ? (q3 ? -P2.sd : P2.sd) : P2.c0;
    float Y = q2 ? P2.cd : (q3 ? P2.s0 : -P2.s0);
    f32x2 Xv = {X, X}, Yv = {Y, Y};
#pragma unroll
    for (int s = 0; s < 2; ++s) BFLY_S(dpp2<0x128>, s, Xv, Yv);
  }

  // ---- G3 = D3_2(q2,q3) * D1_3(q3, q0=group)
  PC P3 = LOADPC(3);
  {
    float ur = q2 ? P2.c4 : 1.f;
    float ui = q2 ? (q3 ? P2.s4 : -P2.s4) : 0.f;
    float dr = q3 ? P3.cA : P3.cB;
    float di = q3 ? P3.sA : P3.sB;  // sign: group A -, group B +
    f32x2 zA = {ur*dr + ui*di, ui*dr - ur*di};   // (re, im)
    f32x2 zB = {ur*dr - ui*di, ui*dr + ur*di};
    f32x2 zAr = {zA.x, zA.x}, zAi = {zA.y, zA.y};
    f32x2 zBr = {zB.x, zB.x}, zBi = {zB.y, zB.y};
#pragma unroll
    for (int s = 0; s < 2; ++s) {
      diag(RA[s], IA[s], zAr, zAi);
      diag(RB[s], IB[s], zBr, zBi);
    }
  }
  // ---- B3: target q0 (group mix), control q3
  {
    float m00 = q3 ? P3.sd : P3.c0, m01 = q3 ? P3.cd : -P3.s0;
    float m10 = q3 ? P3.cd : P3.s0, m11 = q3 ? -P3.sd : P3.c0;
    f32x2 M00 = {m00,m00}, M01 = {m01,m01}, M10 = {m10,m10}, M11 = {m11,m11};
#pragma unroll
    for (int s = 0; s < 2; ++s) {
      f32x2 nRA = pk_fma(M01, RB[s], pk_mul(M00, RA[s]));
      f32x2 nIA = pk_fma(M01, IB[s], pk_mul(M00, IA[s]));
      f32x2 nRB = pk_fma(M11, RB[s], pk_mul(M10, RA[s]));
      f32x2 nIB = pk_fma(M11, IB[s], pk_mul(M10, IA[s]));
      RA[s]=nRA; IA[s]=nIA; RB[s]=nRB; IB[s]=nIB;
    }
  }

  // ---- G4 = D3_3(q3, q0=group) * D1_4(q3,q4)
  PC P4 = LOADPC(4);
  {
    float ar = q3 ? P3.c4 : 1.f;
    float ai = q3 ? P3.s4 : 0.f;  // group A: -ai, B: +ai
    float wr = q3 ? P4.cA : P4.cB;
    float wi = (q4 ? 1.f : -1.f) * (q3 ? P4.sA : P4.sB);
    f32x2 zAr = {ar*wr + ai*wi, ar*wr + ai*wi}, zAi = {ar*wi - ai*wr, ar*wi - ai*wr};
    f32x2 zBr = {ar*wr - ai*wi, ar*wr - ai*wi}, zBi = {ar*wi + ai*wr, ar*wi + ai*wr};
#pragma unroll
    for (int s = 0; s < 2; ++s) {
      diag(RA[s], IA[s], zAr, zAi);
      diag(RB[s], IB[s], zBr, zBi);
    }
  }
  // ---- B4: target q4 (bit4 -> xor16 = ds_swizzle), control q3
  {
    float X = q3 ? (q4 ? -P4.sd : P4.sd) : P4.c0;
    float Y = q3 ? P4.cd : (q4 ? P4.s0 : -P4.s0);
    f32x2 Xv = {X, X}, Yv = {Y, Y};
#pragma unroll
    for (int s = 0; s < 2; ++s) BFLY_S(swz2<0x401F>, s, Xv, Yv);
  }

  // ---- G5 = D3_4(q3,q4) * D1_5(q4,q5)
  PC P5 = LOADPC(5);
  {
    float ur = q3 ? P4.c4 : 1.f;
    float ui = q3 ? (q4 ? P4.s4 : -P4.s4) : 0.f;
    float wr = q4 ? P5.cA : P5.cB;
    float wi = (q5 ? 1.f : -1.f) * (q4 ? P5.sA : P5.sB);
    f32x2 zr = {ur*wr - ui*wi, ur*wr - ui*wi};
    f32x2 zi = {ur*wi + ui*wr, ur*wi + ui*wr};
#pragma unroll
    for (int s = 0; s < 2; ++s) { diag(RA[s],IA[s],zr,zi); diag(RB[s],IB[s],zr,zi); }
  }
  // ---- B5: target q5 (bit2 -> xor4 = ds_swizzle), control q4
  {
    float X = q4 ? (q5 ? -P5.sd : P5.sd) : P5.c0;
    float Y = q4 ? P5.cd : (q5 ? P5.s0 : -P5.s0);
    f32x2 Xv = {X, X}, Yv = {Y, Y};
#pragma unroll
    for (int s = 0; s < 2; ++s) BFLY_S(swz2<0x101F>, s, Xv, Yv);
  }

  // ---- G6 = D3_5(q4,q5) * D1_6(q5,q6)
  PC P6 = LOADPC(6);
  {
    float ur = q4 ? P5.c4 : 1.f;
    float ui = q4 ? (q5 ? P5.s4 : -P5.s4) : 0.f;
    float wr = q5 ? P6.cA : P6.cB;
    float wi = (q6 ? 1.f : -1.f) * (q5 ? P6.sA : P6.sB);
    f32x2 zr = {ur*wr - ui*wi, ur*wr - ui*wi};
    f32x2 zi = {ur*wi + ui*wr, ur*wi + ui*wr};
#pragma unroll
    for (int s = 0; s < 2; ++s) { diag(RA[s],IA[s],zr,zi); diag(RB[s],IB[s],zr,zi); }
  }
  // ---- B6: target q6 (bit1 -> xor2 = DPP quad_perm [2,3,0,1]), control q5
  {
    float X = q5 ? (q6 ? -P6.sd : P6.sd) : P6.c0;
    float Y = q5 ? P6.cd : (q6 ? P6.s0 : -P6.s0);
    f32x2 Xv = {X, X}, Yv = {Y, Y};
#pragma unroll
    for (int s = 0; s < 2; ++s) BFLY_S(dpp2<0x4E>, s, Xv, Yv);
  }

  // ---- G7 = D3_6(q5,q6) * D1_7(q6,q7)
  PC P7 = LOADPC(7);
  {
    float ur = q5 ? P6.c4 : 1.f;
    float ui = q5 ? (q6 ? P6.s4 : -P6.s4) : 0.f;
    float wr = q6 ? P7.cA : P7.cB;
    float wi = (q7 ? 1.f : -1.f) * (q6 ? P7.sA : P7.sB);
    f32x2 zr = {ur*wr - ui*wi, ur*wr - ui*wi};
    f32x2 zi = {ur*wi + ui*wr, ur*wi + ui*wr};
#pragma unroll
    for (int s = 0; s < 2; ++s) { diag(RA[s],IA[s],zr,zi); diag(RB[s],IB[s],zr,zi); }
  }
  // ---- B7: target q7 (bit0 -> xor1 = DPP quad_perm [1,0,3,2]), control q6
  {
    float X = q6 ? (q7 ? -P7.sd : P7.sd) : P7.c0;
    float Y = q6 ? P7.cd : (q7 ? P7.s0 : -P7.s0);
    f32x2 Xv = {X, X}, Yv = {Y, Y};
#pragma unroll
    for (int s = 0; s < 2; ++s) BFLY_S(dpp2<0xB1>, s, Xv, Yv);
  }

  // ---- G8 = D3_7(q6,q7) * D1_8(q7,q3)
  PC P8 = LOADPC(8);
  {
    float ur = q6 ? P7.c4 : 1.f;
    float ui = q6 ? (q7 ? P7.s4 : -P7.s4) : 0.f;
    float wr = q7 ? P8.cA : P8.cB;
    float wi = (q3 ? 1.f : -1.f) * (q7 ? P8.sA : P8.sB);
    f32x2 zr = {ur*wr - ui*wi, ur*wr - ui*wi};
    f32x2 zi = {ur*wi + ui*wr, ur*wi + ui*wr};
#pragma unroll
    for (int s = 0; s < 2; ++s) { diag(RA[s],IA[s],zr,zi); diag(RB[s],IB[s],zr,zi); }
  }
  // ---- B8: target q3 (bit3 -> xor8 = DPP row_ror:8), control q7.
  //      Final D3 of pair8 dropped (pure phase, probs invariant).
  {
    float X = q7 ? (q3 ? -P8.sd : P8.sd) : P8.c0;
    float Y = q7 ? P8.cd : (q3 ? P8.s0 : -P8.s0);
    f32x2 Xv = {X, X}, Yv = {Y, Y};
#pragma unroll
    for (int s = 0; s < 2; ++s) BFLY_S(dpp2<0x128>, s, Xv, Yv);
  }

  // ---- probs over wires 3..7: sum |amp|^2 over q0 (groups), q1 (components),
  //      q2 (lane bit5). Full-wave coalesced store, out idx = q3*16+q4*8+q5*4+q6*2+q7.
  float loc[2];
#pragma unroll
  for (int s = 0; s < 2; ++s) {
    f32x2 acc = pk_fma(RA[s], RA[s],
                 pk_fma(IA[s], IA[s],
                  pk_fma(RB[s], RB[s], pk_mul(IB[s], IB[s]))));
    float l = acc.x + acc.y;
    loc[s] = l + __shfl_xor(l, 32, 64);
  }
  int oidx = ((lane >> 3) & 1) * 16 + ((lane >> 4) & 1) * 8 + (lane & 7);
  out[wv * 64 + (lane & 32) + oidx] = (lane < 32) ? loc[0] : loc[1];
}

extern "C" void kernel_launch(void* const* d_in, const int* in_sizes, int n_in,
                              void* d_out, int out_size, void* d_ws, size_t ws_size,
                              hipStream_t stream) {
  const float* inputs = (const float*)d_in[0];   // (B, 8) f32
  const float* weights = (const float*)d_in[1];  // (1, 45) f32
  float* out = (float*)d_out;                    // (B, 32) f32
  const int B = in_sizes[0] / 8;

  hipLaunchKernelGGL(qnn_main, dim3(B / 8), dim3(256), 0, stream,
                     inputs, weights, out);
}

// Round 6
// 27.724 us; speedup vs baseline: 1.3662x; 1.0511x over previous
//
#include <hip/hip_runtime.h>

typedef float f32x2 __attribute__((ext_vector_type(2)));
#define HALF_INV2PI 0.07957747154594766788f

// ---------------------------------------------------------------------------
// VOP3P packed f32 helpers. All sources are 64-bit register pairs (scalar
// operands must be splatted first — single-VGPR src0 does not assemble).
// ---------------------------------------------------------------------------
__device__ __forceinline__ f32x2 pk_mul(f32x2 a, f32x2 b) {
  f32x2 d; asm("v_pk_mul_f32 %0, %1, %2" : "=v"(d) : "v"(a), "v"(b)); return d;
}
__device__ __forceinline__ f32x2 pk_fma(f32x2 a, f32x2 b, f32x2 c) {
  f32x2 d; asm("v_pk_fma_f32 %0, %1, %2, %3" : "=v"(d) : "v"(a), "v"(b), "v"(c));
  return d;
}
__device__ __forceinline__ f32x2 pk_fms(f32x2 a, f32x2 b, f32x2 c) {
  f32x2 d; asm("v_pk_fma_f32 %0, %1, %2, %3 neg_lo:[0,0,1] neg_hi:[0,0,1]"
               : "=v"(d) : "v"(a), "v"(b), "v"(c));
  return d;
}
// a * swap(b) + c  (op_sel swaps halves of src1)
__device__ __forceinline__ f32x2 pk_fma_sw(f32x2 a, f32x2 b, f32x2 c) {
  f32x2 d; asm("v_pk_fma_f32 %0, %1, %2, %3 op_sel:[0,1,0] op_sel_hi:[1,0,1]"
               : "=v"(d) : "v"(a), "v"(b), "v"(c));
  return d;
}
__device__ __forceinline__ f32x2 sp(float a) { return (f32x2){a, a}; }
#define pk_mul_s(a, b)       pk_mul(sp(a), (b))
#define pk_fma_s(a, b, c)    pk_fma(sp(a), (b), (c))
#define pk_fms_s(a, b, c)    pk_fms(sp(a), (b), (c))
#define pk_fma_sw_s(a, b, c) pk_fma_sw(sp(a), (b), (c))

__device__ __forceinline__ void hw_sc(float rev, float& s, float& c) {
  s = __builtin_amdgcn_sinf(rev);
  c = __builtin_amdgcn_cosf(rev);
}

template<int J>
__device__ __forceinline__ float rl(float x) {
  return __int_as_float(__builtin_amdgcn_readlane(__float_as_int(x), J));
}
struct PC { float cB,sB,cA,sA,c0,s0,cd,sd,c4,s4; };
template<int J>
__device__ __forceinline__ PC loadpc(float cB,float sB,float cA,float sA,
                                     float c0,float s0,float cd,float sd,
                                     float c4,float s4) {
  PC c;
  c.cB=rl<J>(cB); c.sB=rl<J>(sB); c.cA=rl<J>(cA); c.sA=rl<J>(sA);
  c.c0=rl<J>(c0); c.s0=rl<J>(s0); c.cd=rl<J>(cd); c.sd=rl<J>(sd);
  c.c4=rl<J>(c4); c.s4=rl<J>(s4);
  return c;
}

template<int CTRL>
__device__ __forceinline__ f32x2 dpp2(f32x2 v) {
  int x = __builtin_amdgcn_mov_dpp(__float_as_int(v.x), CTRL, 0xf, 0xf, true);
  int y = __builtin_amdgcn_mov_dpp(__float_as_int(v.y), CTRL, 0xf, 0xf, true);
  return (f32x2){__int_as_float(x), __int_as_float(y)};
}
template<int OFF>
__device__ __forceinline__ f32x2 swz2(f32x2 v) {
  int x = __builtin_amdgcn_ds_swizzle(__float_as_int(v.x), OFF);
  int y = __builtin_amdgcn_ds_swizzle(__float_as_int(v.y), OFF);
  return (f32x2){__int_as_float(x), __int_as_float(y)};
}

// complex phase multiply; V = vector phase (per-component), S = scalar phase
#define DIAGV(R, I, zr, zi) do { \
    f32x2 _nR = pk_fms((zr), R, pk_mul((zi), I)); \
    I = pk_fma((zi), R, pk_mul((zr), I)); \
    R = _nR; } while (0)
#define DIAGS(R, I, zr, zi) do { \
    f32x2 _zr = sp(zr), _zi = sp(zi); \
    f32x2 _nR = pk_fms(_zr, R, pk_mul(_zi, I)); \
    I = pk_fma(_zi, R, pk_mul(_zr, I)); \
    R = _nR; } while (0)

// butterfly over a lane bit: v' = X*v + Y*shuf(v), scalar X,Y for all 8 regs
#define BFLY8(SHUF, X, Y) do { \
    f32x2 _X = sp(X), _Y = sp(Y), _o; \
    _o = SHUF(RA0); RA0 = pk_fma(_Y, _o, pk_mul(_X, RA0)); \
    _o = SHUF(IA0); IA0 = pk_fma(_Y, _o, pk_mul(_X, IA0)); \
    _o = SHUF(RB0); RB0 = pk_fma(_Y, _o, pk_mul(_X, RB0)); \
    _o = SHUF(IB0); IB0 = pk_fma(_Y, _o, pk_mul(_X, IB0)); \
    _o = SHUF(RA1); RA1 = pk_fma(_Y, _o, pk_mul(_X, RA1)); \
    _o = SHUF(IA1); IA1 = pk_fma(_Y, _o, pk_mul(_X, IA1)); \
    _o = SHUF(RB1); RB1 = pk_fma(_Y, _o, pk_mul(_X, RB1)); \
    _o = SHUF(IB1); IB1 = pk_fma(_Y, _o, pk_mul(_X, IB1)); \
  } while (0)

// ---------------------------------------------------------------------------
// Layout: lane bit5 = sample (2 samples/wave). Per lane 8 complex amps:
//   register sets {A,B} = q0, {0,1} = q2; f32x2 components .x/.y = q1.
// Lane bits: q4=bit4, q3=bit3, q7=bit2, q6=bit1, q5=bit0.
//   q3 -> xor8  (DPP row_ror:8, butterflied twice)
//   q5 -> xor1  (DPP quad_perm [1,0,3,2])
//   q6 -> xor2  (DPP quad_perm [2,3,0,1])
//   q4 -> xor16 (ds_swizzle), q7 -> xor4 (ds_swizzle)
// ---------------------------------------------------------------------------
__global__ __launch_bounds__(256, 5) void qnn_main(const float* __restrict__ in,
                                                   const float* __restrict__ w,
                                                   float* __restrict__ out) {
  const int tid = threadIdx.x;
  const int wid = tid >> 6;
  const int lane = tid & 63;
  const int wv = blockIdx.x * 4 + wid;
  const int b0 = wv * 2;
  const int q4 = (lane >> 4) & 1, q3 = (lane >> 3) & 1,
            q7 = (lane >> 2) & 1, q6 = (lane >> 1) & 1, q5 = lane & 1;
  const float sgn3 = q3 ? 1.f : -1.f;

  // ---- in-kernel prep: lane j (j<9) computes pair j's 10 gate constants
  float gcB,gsB,gcA,gsA,gc0,gs0,gcd,gsd,gc4,gs4;
  {
    const int jj = (lane < 9) ? lane : 0;
    const float* wp = w + jj * 5;
    float w0 = wp[0], w1 = wp[1], w2 = wp[2], w3 = wp[3], w4 = wp[4];
    hw_sc(w0 * HALF_INV2PI, gsB, gcB);
    hw_sc((w0 + w1) * HALF_INV2PI, gsA, gcA);
    hw_sc((w2 + w3) * HALF_INV2PI, gs0, gc0);
    hw_sc((w2 - w3) * HALF_INV2PI, gsd, gcd);
    hw_sc(w4 * HALF_INV2PI, gs4, gc4);
  }
#define LOADPC(J) loadpc<J>(gcB,gsB,gcA,gsA,gc0,gs0,gcd,gsd,gc4,gs4)

  // ---- embedding: this lane's sample = b0 + (lane>>5); product state (real)
  const float* ip = in + (b0 + (lane >> 5)) * 8;
  float4 A4 = ((const float4*)ip)[0], B4 = ((const float4*)ip)[1];
  float xs[8] = {A4.x, A4.y, A4.z, A4.w, B4.x, B4.y, B4.z, B4.w};
  float vc[8], vs[8];
#pragma unroll
  for (int q = 0; q < 8; ++q)
    hw_sc(__builtin_fmaf(xs[q], HALF_INV2PI, 0.125f), vs[q], vc[q]);
  float prodL = (q3 ? vs[3] : vc[3]) * (q4 ? vs[4] : vc[4]);
  prodL *= (q5 ? vs[5] : vc[5]) * (q6 ? vs[6] : vc[6]);
  prodL *= (q7 ? vs[7] : vc[7]);
  float pA = prodL * vc[0], pB = prodL * vs[0];
  f32x2 vq1 = {vc[1], vs[1]};
  f32x2 bA0 = pk_mul_s(pA * vc[2], vq1), bA1 = pk_mul_s(pA * vs[2], vq1);
  f32x2 bB0 = pk_mul_s(pB * vc[2], vq1), bB1 = pk_mul_s(pB * vs[2], vq1);

  f32x2 RA0, RA1, RB0, RB1, IA0, IA1, IB0, IB1;

  // ---- G0 = D1 of pair0 (c=q0,t=q1) on real state; B0: target q1 (op_sel swap)
  PC P0 = LOADPC(0);
  {
    f32x2 mB = {-P0.sB, P0.sB}, mA = {-P0.sA, P0.sA};
    f32x2 offA = {-P0.s0, P0.s0}, dgB = {P0.sd, -P0.sd};
    f32x2 r, i;
    r = pk_mul_s(P0.cB, bA0); i = pk_mul(mB, bA0);
    RA0 = pk_fma_sw(offA, r, pk_mul_s(P0.c0, r));
    IA0 = pk_fma_sw(offA, i, pk_mul_s(P0.c0, i));
    r = pk_mul_s(P0.cB, bA1); i = pk_mul(mB, bA1);
    RA1 = pk_fma_sw(offA, r, pk_mul_s(P0.c0, r));
    IA1 = pk_fma_sw(offA, i, pk_mul_s(P0.c0, i));
    r = pk_mul_s(P0.cA, bB0); i = pk_mul(mA, bB0);
    RB0 = pk_fma_sw_s(P0.cd, r, pk_mul(dgB, r));
    IB0 = pk_fma_sw_s(P0.cd, i, pk_mul(dgB, i));
    r = pk_mul_s(P0.cA, bB1); i = pk_mul(mA, bB1);
    RB1 = pk_fma_sw_s(P0.cd, r, pk_mul(dgB, r));
    IB1 = pk_fma_sw_s(P0.cd, i, pk_mul(dgB, i));
  }

  // ---- G1 = D3_0(q0,q1) * D1_1(c=q1,t=q2): q2 static -> conj pair of phases
  PC P1 = LOADPC(1);
  {
    f32x2 zr  = {P1.cB, P1.cA};
    f32x2 zi1 = {P1.sB, P1.sA};
    f32x2 zi0 = {-P1.sB, -P1.sA};
    f32x2 d3i = {-P0.s4, P0.s4};
    f32x2 zrB0 = pk_fms_s(P0.c4, zr, pk_mul(d3i, zi0));
    f32x2 ziB0 = pk_fma(d3i, zr, pk_mul_s(P0.c4, zi0));
    f32x2 zrB1 = pk_fms_s(P0.c4, zr, pk_mul(d3i, zi1));
    f32x2 ziB1 = pk_fma(d3i, zr, pk_mul_s(P0.c4, zi1));
    DIAGV(RA0, IA0, zr, zi0);
    DIAGV(RA1, IA1, zr, zi1);
    DIAGV(RB0, IB0, zrB0, ziB0);
    DIAGV(RB1, IB1, zrB1, ziB1);
  }
  // ---- B1: target q2 = register mix between sets, control q1 (component)
  {
    f32x2 m00 = {P1.c0, P1.sd}, m01 = {-P1.s0, P1.cd};
    f32x2 m10 = {P1.s0, P1.cd}, m11 = {P1.c0, -P1.sd};
    f32x2 t;
    t   = pk_fma(m01, RA1, pk_mul(m00, RA0));
    RA1 = pk_fma(m11, RA1, pk_mul(m10, RA0)); RA0 = t;
    t   = pk_fma(m01, IA1, pk_mul(m00, IA0));
    IA1 = pk_fma(m11, IA1, pk_mul(m10, IA0)); IA0 = t;
    t   = pk_fma(m01, RB1, pk_mul(m00, RB0));
    RB1 = pk_fma(m11, RB1, pk_mul(m10, RB0)); RB0 = t;
    t   = pk_fma(m01, IB1, pk_mul(m00, IB0));
    IB1 = pk_fma(m11, IB1, pk_mul(m10, IB0)); IB0 = t;
  }

  // ---- G2 = D3_1(c=q1,t=q2) * D1_2(c=q2,t=q3)
  PC P2 = LOADPC(2);
  {
    float wi0 = sgn3 * P2.sB, wi1 = sgn3 * P2.sA;
    f32x2 zr0 = {P2.cB, __builtin_fmaf(P1.s4, wi0, P1.c4 * P2.cB)};
    f32x2 zi0 = {wi0,   __builtin_fmaf(P1.c4, wi0, -P1.s4 * P2.cB)};
    f32x2 zr1 = {P2.cA, __builtin_fmaf(-P1.s4, wi1, P1.c4 * P2.cA)};
    f32x2 zi1 = {wi1,   __builtin_fmaf(P1.c4, wi1, P1.s4 * P2.cA)};
    DIAGV(RA0, IA0, zr0, zi0); DIAGV(RB0, IB0, zr0, zi0);
    DIAGV(RA1, IA1, zr1, zi1); DIAGV(RB1, IB1, zr1, zi1);
  }
  // ---- B2: target q3 (DPP ror8), control q2 (static per set)
  {
    float Y0 = q3 ? P2.s0 : -P2.s0;
    float X1 = q3 ? -P2.sd : P2.sd;
    f32x2 c0v = sp(P2.c0), Y0v = sp(Y0), X1v = sp(X1), cdv = sp(P2.cd), o;
    o = dpp2<0x128>(RA0); RA0 = pk_fma(Y0v, o, pk_mul(c0v, RA0));
    o = dpp2<0x128>(IA0); IA0 = pk_fma(Y0v, o, pk_mul(c0v, IA0));
    o = dpp2<0x128>(RB0); RB0 = pk_fma(Y0v, o, pk_mul(c0v, RB0));
    o = dpp2<0x128>(IB0); IB0 = pk_fma(Y0v, o, pk_mul(c0v, IB0));
    o = dpp2<0x128>(RA1); RA1 = pk_fma(cdv, o, pk_mul(X1v, RA1));
    o = dpp2<0x128>(IA1); IA1 = pk_fma(cdv, o, pk_mul(X1v, IA1));
    o = dpp2<0x128>(RB1); RB1 = pk_fma(cdv, o, pk_mul(X1v, RB1));
    o = dpp2<0x128>(IB1); IB1 = pk_fma(cdv, o, pk_mul(X1v, IB1));
  }

  // ---- G3 = D3_2(c=q2,t=q3) * D1_3(c=q3,t=q0)
  PC P3 = LOADPC(3);
  {
    float dr = q3 ? P3.cA : P3.cB;
    float di = q3 ? P3.sA : P3.sB;
    float ndi = -di;
    float ui2 = sgn3 * P2.s4;
    float zA1r = __builtin_fmaf(ui2, di, P2.c4 * dr);
    float zA1i = __builtin_fmaf(ui2, dr, -P2.c4 * di);
    float zB1r = __builtin_fmaf(-ui2, di, P2.c4 * dr);
    float zB1i = __builtin_fmaf(ui2, dr, P2.c4 * di);
    DIAGS(RA0, IA0, dr, ndi);
    DIAGS(RB0, IB0, dr, di);
    DIAGS(RA1, IA1, zA1r, zA1i);
    DIAGS(RB1, IB1, zB1r, zB1i);
  }
  // ---- B3: target q0 (A<->B register mix), control q3
  {
    float m00 = q3 ? P3.sd : P3.c0, m01 = q3 ? P3.cd : -P3.s0;
    float m10 = q3 ? P3.cd : P3.s0, m11 = q3 ? -P3.sd : P3.c0;
    f32x2 M00 = sp(m00), M01 = sp(m01), M10 = sp(m10), M11 = sp(m11), t;
    t   = pk_fma(M01, RB0, pk_mul(M00, RA0));
    RB0 = pk_fma(M11, RB0, pk_mul(M10, RA0)); RA0 = t;
    t   = pk_fma(M01, IB0, pk_mul(M00, IA0));
    IB0 = pk_fma(M11, IB0, pk_mul(M10, IA0)); IA0 = t;
    t   = pk_fma(M01, RB1, pk_mul(M00, RA1));
    RB1 = pk_fma(M11, RB1, pk_mul(M10, RA1)); RA1 = t;
    t   = pk_fma(M01, IB1, pk_mul(M00, IA1));
    IB1 = pk_fma(M11, IB1, pk_mul(M10, IA1)); IA1 = t;
  }

  // ---- G4 = D3_3(c=q3,t=q0) * D1_4(c=q3,t=q4)
  PC P4 = LOADPC(4);
  {
    float ar = q3 ? P3.c4 : 1.f;
    float ai = q3 ? P3.s4 : 0.f;
    float wr = q3 ? P4.cA : P4.cB;
    float wi = (q4 ? 1.f : -1.f) * (q3 ? P4.sA : P4.sB);
    float zAr = __builtin_fmaf(ai, wi, ar * wr);
    float zAi = __builtin_fmaf(-ai, wr, ar * wi);
    float zBr = __builtin_fmaf(-ai, wi, ar * wr);
    float zBi = __builtin_fmaf(ai, wr, ar * wi);
    DIAGS(RA0, IA0, zAr, zAi); DIAGS(RA1, IA1, zAr, zAi);
    DIAGS(RB0, IB0, zBr, zBi); DIAGS(RB1, IB1, zBr, zBi);
  }
  // ---- B4: target q4 (xor16, ds_swizzle), control q3
  {
    float X = q3 ? (q4 ? -P4.sd : P4.sd) : P4.c0;
    float Y = q3 ? P4.cd : (q4 ? P4.s0 : -P4.s0);
    BFLY8(swz2<0x401F>, X, Y);
  }

  // ---- G5 = D3_4(c=q3,t=q4) * D1_5(c=q4,t=q5)
  PC P5 = LOADPC(5);
  {
    float ur = q3 ? P4.c4 : 1.f;
    float ui = q3 ? (q4 ? P4.s4 : -P4.s4) : 0.f;
    float wr = q4 ? P5.cA : P5.cB;
    float wi = (q5 ? 1.f : -1.f) * (q4 ? P5.sA : P5.sB);
    float zr = __builtin_fmaf(-ui, wi, ur * wr);
    float zi = __builtin_fmaf(ui, wr, ur * wi);
    DIAGS(RA0, IA0, zr, zi); DIAGS(RA1, IA1, zr, zi);
    DIAGS(RB0, IB0, zr, zi); DIAGS(RB1, IB1, zr, zi);
  }
  // ---- B5: target q5 (xor1, DPP quad_perm [1,0,3,2]), control q4
  {
    float X = q4 ? (q5 ? -P5.sd : P5.sd) : P5.c0;
    float Y = q4 ? P5.cd : (q5 ? P5.s0 : -P5.s0);
    BFLY8(dpp2<0xB1>, X, Y);
  }

  // ---- G6 = D3_5(c=q4,t=q5) * D1_6(c=q5,t=q6)
  PC P6 = LOADPC(6);
  {
    float ur = q4 ? P5.c4 : 1.f;
    float ui = q4 ? (q5 ? P5.s4 : -P5.s4) : 0.f;
    float wr = q5 ? P6.cA : P6.cB;
    float wi = (q6 ? 1.f : -1.f) * (q5 ? P6.sA : P6.sB);
    float zr = __builtin_fmaf(-ui, wi, ur * wr);
    float zi = __builtin_fmaf(ui, wr, ur * wi);
    DIAGS(RA0, IA0, zr, zi); DIAGS(RA1, IA1, zr, zi);
    DIAGS(RB0, IB0, zr, zi); DIAGS(RB1, IB1, zr, zi);
  }
  // ---- B6: target q6 (xor2, DPP quad_perm [2,3,0,1]), control q5
  {
    float X = q5 ? (q6 ? -P6.sd : P6.sd) : P6.c0;
    float Y = q5 ? P6.cd : (q6 ? P6.s0 : -P6.s0);
    BFLY8(dpp2<0x4E>, X, Y);
  }

  // ---- G7 = D3_6(c=q5,t=q6) * D1_7(c=q6,t=q7)
  PC P7 = LOADPC(7);
  {
    float ur = q5 ? P6.c4 : 1.f;
    float ui = q5 ? (q6 ? P6.s4 : -P6.s4) : 0.f;
    float wr = q6 ? P7.cA : P7.cB;
    float wi = (q7 ? 1.f : -1.f) * (q6 ? P7.sA : P7.sB);
    float zr = __builtin_fmaf(-ui, wi, ur * wr);
    float zi = __builtin_fmaf(ui, wr, ur * wi);
    DIAGS(RA0, IA0, zr, zi); DIAGS(RA1, IA1, zr, zi);
    DIAGS(RB0, IB0, zr, zi); DIAGS(RB1, IB1, zr, zi);
  }
  // ---- B7: target q7 (xor4, ds_swizzle), control q6
  {
    float X = q6 ? (q7 ? -P7.sd : P7.sd) : P7.c0;
    float Y = q6 ? P7.cd : (q7 ? P7.s0 : -P7.s0);
    BFLY8(swz2<0x101F>, X, Y);
  }

  // ---- G8 = D3_7(c=q6,t=q7) * D1_8(c=q7,t=q3)
  PC P8 = LOADPC(8);
  {
    float ur = q6 ? P7.c4 : 1.f;
    float ui = q6 ? (q7 ? P7.s4 : -P7.s4) : 0.f;
    float wr = q7 ? P8.cA : P8.cB;
    float wi = sgn3 * (q7 ? P8.sA : P8.sB);
    float zr = __builtin_fmaf(-ui, wi, ur * wr);
    float zi = __builtin_fmaf(ui, wr, ur * wi);
    DIAGS(RA0, IA0, zr, zi); DIAGS(RA1, IA1, zr, zi);
    DIAGS(RB0, IB0, zr, zi); DIAGS(RB1, IB1, zr, zi);
  }
  // ---- B8: target q3 (DPP ror8), control q7. Final D3 dropped (pure phase).
  {
    float X = q7 ? (q3 ? -P8.sd : P8.sd) : P8.c0;
    float Y = q7 ? P8.cd : (q3 ? P8.s0 : -P8.s0);
    BFLY8(dpp2<0x128>, X, Y);
  }

  // ---- probs: marginalize q0,q1,q2 (all in-thread) -> pure in-lane sum
  f32x2 acc = pk_mul(RA0, RA0);
  acc = pk_fma(IA0, IA0, acc);
  acc = pk_fma(RA1, RA1, acc);
  acc = pk_fma(IA1, IA1, acc);
  acc = pk_fma(RB0, RB0, acc);
  acc = pk_fma(IB0, IB0, acc);
  acc = pk_fma(RB1, RB1, acc);
  acc = pk_fma(IB1, IB1, acc);
  float loc = acc.x + acc.y;
  // out index k = q3*16 + q4*8 + q5*4 + q6*2 + q7
  int k = ((lane >> 3) & 1) * 16 + ((lane >> 4) & 1) * 8 + (lane & 1) * 4
        + (lane & 2) + ((lane >> 2) & 1);
  out[wv * 64 + (lane & 32) + k] = loc;
}

extern "C" void kernel_launch(void* const* d_in, const int* in_sizes, int n_in,
                              void* d_out, int out_size, void* d_ws, size_t ws_size,
                              hipStream_t stream) {
  const float* inputs = (const float*)d_in[0];   // (B, 8) f32
  const float* weights = (const float*)d_in[1];  // (1, 45) f32
  float* out = (float*)d_out;                    // (B, 32) f32
  const int B = in_sizes[0] / 8;

  hipLaunchKernelGGL(qnn_main, dim3(B / 8), dim3(256), 0, stream,
                     inputs, weights, out);
}

// Round 7
// 20.244 us; speedup vs baseline: 1.8711x; 1.3695x over previous
//
#include <hip/hip_runtime.h>

typedef float f32x2 __attribute__((ext_vector_type(2)));
#define HALF_INV2PI 0.07957747154594766788f

// ---------------------------------------------------------------------------
// VOP3P packed f32 helpers (forms verified on gfx950 in rounds 4/6).
// ---------------------------------------------------------------------------
__device__ __forceinline__ f32x2 pk_mul(f32x2 a, f32x2 b) {
  f32x2 d; asm("v_pk_mul_f32 %0, %1, %2" : "=v"(d) : "v"(a), "v"(b)); return d;
}
__device__ __forceinline__ f32x2 pk_fma(f32x2 a, f32x2 b, f32x2 c) {
  f32x2 d; asm("v_pk_fma_f32 %0, %1, %2, %3" : "=v"(d) : "v"(a), "v"(b), "v"(c));
  return d;
}
__device__ __forceinline__ f32x2 pk_fms(f32x2 a, f32x2 b, f32x2 c) {
  f32x2 d; asm("v_pk_fma_f32 %0, %1, %2, %3 neg_lo:[0,0,1] neg_hi:[0,0,1]"
               : "=v"(d) : "v"(a), "v"(b), "v"(c));
  return d;
}
// a * swap(b) + c (op_sel swaps halves of src1)
__device__ __forceinline__ f32x2 pk_fma_sw(f32x2 a, f32x2 b, f32x2 c) {
  f32x2 d; asm("v_pk_fma_f32 %0, %1, %2, %3 op_sel:[0,1,0] op_sel_hi:[1,0,1]"
               : "=v"(d) : "v"(a), "v"(b), "v"(c));
  return d;
}
__device__ __forceinline__ f32x2 sp(float a) { return (f32x2){a, a}; }

__device__ __forceinline__ void hw_sc(float rev, float& s, float& c) {
  s = __builtin_amdgcn_sinf(rev);
  c = __builtin_amdgcn_cosf(rev);
}

template<int J>
__device__ __forceinline__ float rl(float x) {
  return __int_as_float(__builtin_amdgcn_readlane(__float_as_int(x), J));
}
struct PC { float cB,sB,cA,sA,c0,s0,cd,sd,c4,s4; };
template<int J>
__device__ __forceinline__ PC loadpc(float cB,float sB,float cA,float sA,
                                     float c0,float s0,float cd,float sd,
                                     float c4,float s4) {
  PC c;
  c.cB=rl<J>(cB); c.sB=rl<J>(sB); c.cA=rl<J>(cA); c.sA=rl<J>(sA);
  c.c0=rl<J>(c0); c.s0=rl<J>(s0); c.cd=rl<J>(cd); c.sd=rl<J>(sd);
  c.c4=rl<J>(c4); c.s4=rl<J>(s4);
  return c;
}

template<int CTRL>
__device__ __forceinline__ f32x2 dpp2(f32x2 v) {
  int x = __builtin_amdgcn_mov_dpp(__float_as_int(v.x), CTRL, 0xf, 0xf, true);
  int y = __builtin_amdgcn_mov_dpp(__float_as_int(v.y), CTRL, 0xf, 0xf, true);
  return (f32x2){__int_as_float(x), __int_as_float(y)};
}

// complex phase multiply on set s (vector phase over q1 components)
#define CDIAG(s, zr, zi) do { \
    f32x2 _nR = pk_fms((zr), R[s], pk_mul((zi), I[s])); \
    I[s] = pk_fma((zi), R[s], pk_mul((zr), I[s])); \
    R[s] = _nR; } while (0)
#define CDIAGS(s, zr, zi) do { \
    f32x2 _zr = sp(zr), _zi = sp(zi); CDIAG(s, _zr, _zi); } while (0)

// ---------------------------------------------------------------------------
// Layout: 8 samples/wave (sample bits = lane{5,4,2}); per-lane 32 complex amps:
//   register set s = q0*8 + q2*4 + q4*2 + q7  (R[s],I[s]), component .x/.y = q1.
//   Lane qubit bits: q3=bit3 (DPP row_ror:8), q6=bit1 (quad_perm [2,3,0,1]),
//   q5=bit0 (quad_perm [1,0,3,2]).  ZERO ds_swizzle / LDS in the kernel.
// ---------------------------------------------------------------------------
__global__ __launch_bounds__(256, 4) void qnn_main(const float* __restrict__ in,
                                                   const float* __restrict__ w,
                                                   float* __restrict__ out) {
  const int tid = threadIdx.x;
  const int wid = tid >> 6;
  const int lane = tid & 63;
  const int wv = blockIdx.x * 4 + wid;
  const int q3 = (lane >> 3) & 1, q6 = (lane >> 1) & 1, q5 = lane & 1;
  const int smp = ((lane >> 5) & 1) * 4 + ((lane >> 4) & 1) * 2 + ((lane >> 2) & 1);
  const float sgn3 = q3 ? 1.f : -1.f;
  const float sgn5 = q5 ? 1.f : -1.f;
  const float sgn6 = q6 ? 1.f : -1.f;

  // ---- in-kernel prep: lane j (j<9) computes pair j's 10 gate constants
  float gcB,gsB,gcA,gsA,gc0,gs0,gcd,gsd,gc4,gs4;
  {
    const int jj = (lane < 9) ? lane : 0;
    const float* wp = w + jj * 5;
    float w0 = wp[0], w1 = wp[1], w2 = wp[2], w3 = wp[3], w4 = wp[4];
    hw_sc(w0 * HALF_INV2PI, gsB, gcB);
    hw_sc((w0 + w1) * HALF_INV2PI, gsA, gcA);
    hw_sc((w2 + w3) * HALF_INV2PI, gs0, gc0);
    hw_sc((w2 - w3) * HALF_INV2PI, gsd, gcd);
    hw_sc(w4 * HALF_INV2PI, gs4, gc4);
  }
#define LOADPC(J) loadpc<J>(gcB,gsB,gcA,gsA,gc0,gs0,gcd,gsd,gc4,gs4)

  // ---- embedding: this lane's sample; product state, all real
  const float* ip = in + (wv * 8 + smp) * 8;
  float4 A4 = ((const float4*)ip)[0], B4 = ((const float4*)ip)[1];
  float xs[8] = {A4.x, A4.y, A4.z, A4.w, B4.x, B4.y, B4.z, B4.w};
  float vc[8], vs[8];
#pragma unroll
  for (int q = 0; q < 8; ++q)
    hw_sc(__builtin_fmaf(xs[q], HALF_INV2PI, 0.125f), vs[q], vc[q]);
  float prodL = (q3 ? vs[3] : vc[3]) * (q5 ? vs[5] : vc[5]) * (q6 ? vs[6] : vc[6]);
  f32x2 vq1 = {vc[1], vs[1]}, mq1 = {-vc[1], vs[1]};
  float b[16];
  {
    float t0 = prodL * vc[0], t1 = prodL * vs[0];       // q0
    float u[4] = {t0 * vc[2], t0 * vs[2], t1 * vc[2], t1 * vs[2]};  // q0*2+q2
    float z[8];
#pragma unroll
    for (int i = 0; i < 4; ++i) { z[i*2] = u[i]*vc[4]; z[i*2+1] = u[i]*vs[4]; }
#pragma unroll
    for (int i = 0; i < 8; ++i) { b[i*2] = z[i]*vc[7]; b[i*2+1] = z[i]*vs[7]; }
  }

  f32x2 R[16], I[16];

  // ---- G0 = D1_0(c=q0,t=q1) on real state;  B0: target q1 (op_sel swap)
  PC P0 = LOADPC(0);
  {
    f32x2 Y0 = {-P0.s0, P0.s0};         // q0=0 butterfly partner coeff
    f32x2 X1 = {P0.sd, -P0.sd};         // q0=1 butterfly diag coeff
    f32x2 c0v = sp(P0.c0), cdv = sp(P0.cd);
#pragma unroll
    for (int s = 0; s < 16; ++s) {
      const bool Q0 = (s & 8) != 0;
      float br = b[s] * (Q0 ? P0.cA : P0.cB);
      float bi = b[s] * (Q0 ? P0.sA : P0.sB);
      f32x2 r = pk_mul(sp(br), vq1);
      f32x2 i = pk_mul(sp(bi), mq1);
      if (!Q0) {
        R[s] = pk_fma_sw(Y0, r, pk_mul(c0v, r));
        I[s] = pk_fma_sw(Y0, i, pk_mul(c0v, i));
      } else {
        R[s] = pk_fma_sw(cdv, r, pk_mul(X1, r));
        I[s] = pk_fma_sw(cdv, i, pk_mul(X1, i));
      }
    }
  }

  // ---- G1 = D3_0(c=q0,t=q1) * D1_1(c=q1,t=q2)
  PC P1 = LOADPC(1);
  {
    f32x2 zr1 = {P1.cB, P1.cA};
    f32x2 zi1q[2] = {{-P1.sB, -P1.sA}, {P1.sB, P1.sA}};   // by q2
    f32x2 d3i = {-P0.s4, P0.s4};
    f32x2 c4v = sp(P0.c4);
    f32x2 zrB[2], ziB[2];
#pragma unroll
    for (int t = 0; t < 2; ++t) {
      zrB[t] = pk_fms(c4v, zr1, pk_mul(d3i, zi1q[t]));
      ziB[t] = pk_fma(d3i, zr1, pk_mul(c4v, zi1q[t]));
    }
#pragma unroll
    for (int s = 0; s < 16; ++s) {
      const int Q2 = (s >> 2) & 1;
      if (s & 8) { CDIAG(s, zrB[Q2], ziB[Q2]); }
      else       { CDIAG(s, zr1, zi1q[Q2]); }
    }
  }
  // ---- B1: target q2 (register mix s<->s|4), control q1 (component vector)
  {
    f32x2 m00 = {P1.c0, P1.sd}, m01 = {-P1.s0, P1.cd};
    f32x2 m10 = {P1.s0, P1.cd}, m11 = {P1.c0, -P1.sd};
#pragma unroll
    for (int s = 0; s < 16; ++s) {
      if (s & 4) continue;
      const int a = s, c = s | 4;
      f32x2 t;
      t    = pk_fma(m01, R[c], pk_mul(m00, R[a]));
      R[c] = pk_fma(m11, R[c], pk_mul(m10, R[a])); R[a] = t;
      t    = pk_fma(m01, I[c], pk_mul(m00, I[a]));
      I[c] = pk_fma(m11, I[c], pk_mul(m10, I[a])); I[a] = t;
    }
  }

  // ---- G2 = D3_1(c=q1,t=q2) * D1_2(c=q2,t=q3)
  PC P2 = LOADPC(2);
  {
    float wr0 = P2.cB, wi0 = sgn3 * P2.sB;
    float wr1 = P2.cA, wi1 = sgn3 * P2.sA;
    f32x2 zrq[2] = {{wr0, __builtin_fmaf(P1.s4, wi0, P1.c4*wr0)},
                    {wr1, __builtin_fmaf(-P1.s4, wi1, P1.c4*wr1)}};
    f32x2 ziq[2] = {{wi0, __builtin_fmaf(P1.c4, wi0, -P1.s4*wr0)},
                    {wi1, __builtin_fmaf(P1.c4, wi1,  P1.s4*wr1)}};
#pragma unroll
    for (int s = 0; s < 16; ++s) {
      const int Q2 = (s >> 2) & 1;
      CDIAG(s, zrq[Q2], ziq[Q2]);
    }
  }
  // ---- B2: target q3 (DPP ror8), control q2 (set bit)
  {
    float Y0 = q3 ? P2.s0 : -P2.s0;
    float X1 = q3 ? -P2.sd : P2.sd;
    f32x2 Xv[2] = {sp(P2.c0), sp(X1)};
    f32x2 Yv[2] = {sp(Y0), sp(P2.cd)};
#pragma unroll
    for (int s = 0; s < 16; ++s) {
      const int Q2 = (s >> 2) & 1;
      f32x2 o = dpp2<0x128>(R[s]); R[s] = pk_fma(Yv[Q2], o, pk_mul(Xv[Q2], R[s]));
      o = dpp2<0x128>(I[s]);       I[s] = pk_fma(Yv[Q2], o, pk_mul(Xv[Q2], I[s]));
    }
  }

  // ---- G3 = D3_2(c=q2,t=q3) * D1_3(c=q3,t=q0)
  PC P3 = LOADPC(3);
  {
    float dr = q3 ? P3.cA : P3.cB;
    float di = q3 ? P3.sA : P3.sB;
    float ui = sgn3 * P2.s4;
    float zr_[2][2], zi_[2][2];          // [q2][q0]
    zr_[0][0] = dr;  zi_[0][0] = -di;
    zr_[0][1] = dr;  zi_[0][1] =  di;
    zr_[1][0] = __builtin_fmaf(ui, di, P2.c4*dr);
    zi_[1][0] = __builtin_fmaf(ui, dr, -P2.c4*di);
    zr_[1][1] = __builtin_fmaf(-ui, di, P2.c4*dr);
    zi_[1][1] = __builtin_fmaf(ui, dr,  P2.c4*di);
#pragma unroll
    for (int s = 0; s < 16; ++s) {
      const int Q2 = (s >> 2) & 1, Q0 = (s >> 3) & 1;
      CDIAGS(s, zr_[Q2][Q0], zi_[Q2][Q0]);
    }
  }
  // ---- B3: target q0 (register mix s<->s|8), control q3 (lane)
  {
    float m00 = q3 ? P3.sd : P3.c0, m01 = q3 ? P3.cd : -P3.s0;
    float m10 = q3 ? P3.cd : P3.s0, m11 = q3 ? -P3.sd : P3.c0;
    f32x2 M00 = sp(m00), M01 = sp(m01), M10 = sp(m10), M11 = sp(m11);
#pragma unroll
    for (int s = 0; s < 8; ++s) {
      const int a = s, c = s | 8;
      f32x2 t;
      t    = pk_fma(M01, R[c], pk_mul(M00, R[a]));
      R[c] = pk_fma(M11, R[c], pk_mul(M10, R[a])); R[a] = t;
      t    = pk_fma(M01, I[c], pk_mul(M00, I[a]));
      I[c] = pk_fma(M11, I[c], pk_mul(M10, I[a])); I[a] = t;
    }
  }

  // ---- G4 = D3_3(c=q3,t=q0) * D1_4(c=q3,t=q4)
  PC P4 = LOADPC(4);
  {
    float ar = q3 ? P3.c4 : 1.f, ai = q3 ? P3.s4 : 0.f;
    float wr = q3 ? P4.cA : P4.cB, wi = q3 ? P4.sA : P4.sB;
    float p = ar*wr, qq = ai*wi, r_ = ar*wi, t_ = ai*wr;
    float zr_[2][2] = {{p - qq, p + qq}, {p + qq, p - qq}};   // [q0][q4]
    float zi_[2][2] = {{-r_ - t_, r_ - t_}, {-r_ + t_, r_ + t_}};
#pragma unroll
    for (int s = 0; s < 16; ++s) {
      const int Q0 = (s >> 3) & 1, Q4 = (s >> 1) & 1;
      CDIAGS(s, zr_[Q0][Q4], zi_[Q0][Q4]);
    }
  }
  // ---- B4: target q4 (register mix s<->s|2), control q3 (lane)
  {
    float m00 = q3 ? P4.sd : P4.c0, m01 = q3 ? P4.cd : -P4.s0;
    float m10 = q3 ? P4.cd : P4.s0, m11 = q3 ? -P4.sd : P4.c0;
    f32x2 M00 = sp(m00), M01 = sp(m01), M10 = sp(m10), M11 = sp(m11);
#pragma unroll
    for (int s = 0; s < 16; ++s) {
      if (s & 2) continue;
      const int a = s, c = s | 2;
      f32x2 t;
      t    = pk_fma(M01, R[c], pk_mul(M00, R[a]));
      R[c] = pk_fma(M11, R[c], pk_mul(M10, R[a])); R[a] = t;
      t    = pk_fma(M01, I[c], pk_mul(M00, I[a]));
      I[c] = pk_fma(M11, I[c], pk_mul(M10, I[a])); I[a] = t;
    }
  }

  // ---- G5 = D3_4(c=q3,t=q4) * D1_5(c=q4,t=q5)
  PC P5 = LOADPC(5);
  {
    float ur = q3 ? P4.c4 : 1.f, ui = q3 ? P4.s4 : 0.f;
    float w0r = P5.cB, w0i = sgn5 * P5.sB;
    float w1r = P5.cA, w1i = sgn5 * P5.sA;
    float zr_[2] = {__builtin_fmaf(ui, w0i, ur*w0r), __builtin_fmaf(-ui, w1i, ur*w1r)};
    float zi_[2] = {__builtin_fmaf(-ui, w0r, ur*w0i), __builtin_fmaf(ui, w1r, ur*w1i)};
#pragma unroll
    for (int s = 0; s < 16; ++s) {
      const int Q4 = (s >> 1) & 1;
      CDIAGS(s, zr_[Q4], zi_[Q4]);
    }
  }
  // ---- B5: target q5 (DPP quad_perm [1,0,3,2]), control q4 (set bit)
  {
    float Y0 = q5 ? P5.s0 : -P5.s0;
    float X1 = q5 ? -P5.sd : P5.sd;
    f32x2 Xv[2] = {sp(P5.c0), sp(X1)};
    f32x2 Yv[2] = {sp(Y0), sp(P5.cd)};
#pragma unroll
    for (int s = 0; s < 16; ++s) {
      const int Q4 = (s >> 1) & 1;
      f32x2 o = dpp2<0xB1>(R[s]); R[s] = pk_fma(Yv[Q4], o, pk_mul(Xv[Q4], R[s]));
      o = dpp2<0xB1>(I[s]);       I[s] = pk_fma(Yv[Q4], o, pk_mul(Xv[Q4], I[s]));
    }
  }

  // ---- G6 = D3_5(c=q4,t=q5) * D1_6(c=q5,t=q6)
  PC P6 = LOADPC(6);
  {
    float wr = q5 ? P6.cA : P6.cB;
    float wi = sgn6 * (q5 ? P6.sA : P6.sB);
    float vi = sgn5 * P5.s4;
    float zr_[2] = {wr, __builtin_fmaf(-vi, wi, P5.c4*wr)};
    float zi_[2] = {wi, __builtin_fmaf(vi, wr, P5.c4*wi)};
#pragma unroll
    for (int s = 0; s < 16; ++s) {
      const int Q4 = (s >> 1) & 1;
      CDIAGS(s, zr_[Q4], zi_[Q4]);
    }
  }
  // ---- B6: target q6 (DPP quad_perm [2,3,0,1]), control q5 (lane)
  {
    float X = q5 ? (q6 ? -P6.sd : P6.sd) : P6.c0;
    float Y = q5 ? P6.cd : (q6 ? P6.s0 : -P6.s0);
    f32x2 Xv = sp(X), Yv = sp(Y);
#pragma unroll
    for (int s = 0; s < 16; ++s) {
      f32x2 o = dpp2<0x4E>(R[s]); R[s] = pk_fma(Yv, o, pk_mul(Xv, R[s]));
      o = dpp2<0x4E>(I[s]);       I[s] = pk_fma(Yv, o, pk_mul(Xv, I[s]));
    }
  }

  // ---- G7 = D3_6(c=q5,t=q6) * D1_7(c=q6,t=q7)
  PC P7 = LOADPC(7);
  {
    float ur = q5 ? P6.c4 : 1.f;
    float vi = sgn6 * (q5 ? P6.s4 : 0.f);
    float wr = q6 ? P7.cA : P7.cB, wi = q6 ? P7.sA : P7.sB;
    float zr_[2] = {__builtin_fmaf(vi, wi, ur*wr), __builtin_fmaf(-vi, wi, ur*wr)};
    float zi_[2] = {__builtin_fmaf(vi, wr, -ur*wi), __builtin_fmaf(vi, wr, ur*wi)};
#pragma unroll
    for (int s = 0; s < 16; ++s) {
      const int Q7 = s & 1;
      CDIAGS(s, zr_[Q7], zi_[Q7]);
    }
  }
  // ---- B7: target q7 (register mix s<->s|1), control q6 (lane)
  {
    float m00 = q6 ? P7.sd : P7.c0, m01 = q6 ? P7.cd : -P7.s0;
    float m10 = q6 ? P7.cd : P7.s0, m11 = q6 ? -P7.sd : P7.c0;
    f32x2 M00 = sp(m00), M01 = sp(m01), M10 = sp(m10), M11 = sp(m11);
#pragma unroll
    for (int s = 0; s < 16; ++s) {
      if (s & 1) continue;
      const int a = s, c = s | 1;
      f32x2 t;
      t    = pk_fma(M01, R[c], pk_mul(M00, R[a]));
      R[c] = pk_fma(M11, R[c], pk_mul(M10, R[a])); R[a] = t;
      t    = pk_fma(M01, I[c], pk_mul(M00, I[a]));
      I[c] = pk_fma(M11, I[c], pk_mul(M10, I[a])); I[a] = t;
    }
  }

  // ---- G8 = D3_7(c=q6,t=q7) * D1_8(c=q7,t=q3)
  PC P8 = LOADPC(8);
  {
    float ur = q6 ? P7.c4 : 1.f, ui = q6 ? P7.s4 : 0.f;
    float w0r = P8.cB, w0i = sgn3 * P8.sB;
    float w1r = P8.cA, w1i = sgn3 * P8.sA;
    float zr_[2] = {__builtin_fmaf(ui, w0i, ur*w0r), __builtin_fmaf(-ui, w1i, ur*w1r)};
    float zi_[2] = {__builtin_fmaf(-ui, w0r, ur*w0i), __builtin_fmaf(ui, w1r, ur*w1i)};
#pragma unroll
    for (int s = 0; s < 16; ++s) {
      const int Q7 = s & 1;
      CDIAGS(s, zr_[Q7], zi_[Q7]);
    }
  }
  // ---- B8: target q3 (DPP ror8), control q7 (set bit). Final D3 dropped.
  {
    float Y0 = q3 ? P8.s0 : -P8.s0;
    float X1 = q3 ? -P8.sd : P8.sd;
    f32x2 Xv[2] = {sp(P8.c0), sp(X1)};
    f32x2 Yv[2] = {sp(Y0), sp(P8.cd)};
#pragma unroll
    for (int s = 0; s < 16; ++s) {
      const int Q7 = s & 1;
      f32x2 o = dpp2<0x128>(R[s]); R[s] = pk_fma(Yv[Q7], o, pk_mul(Xv[Q7], R[s]));
      o = dpp2<0x128>(I[s]);       I[s] = pk_fma(Yv[Q7], o, pk_mul(Xv[Q7], I[s]));
    }
  }

  // ---- probs: marginalize q0 (set bit3), q2 (set bit2), q1 (components) ----
  f32x2 acc[4] = {{0.f,0.f},{0.f,0.f},{0.f,0.f},{0.f,0.f}};
#pragma unroll
  for (int s = 0; s < 16; ++s) {
    acc[s & 3] = pk_fma(R[s], R[s], acc[s & 3]);
    acc[s & 3] = pk_fma(I[s], I[s], acc[s & 3]);
  }
  // out index k = q3*16 + q4*8 + q5*4 + q6*2 + q7 ; acc[j]: j = q4*2 + q7
  const int k0 = q3 * 16 + q5 * 4 + q6 * 2;
  float* ob = out + (wv * 8 + smp) * 32 + k0;
  float2 v0 = make_float2(acc[0].x + acc[0].y, acc[1].x + acc[1].y);
  float2 v1 = make_float2(acc[2].x + acc[2].y, acc[3].x + acc[3].y);
  *(float2*)(ob) = v0;
  *(float2*)(ob + 8) = v1;
}

extern "C" void kernel_launch(void* const* d_in, const int* in_sizes, int n_in,
                              void* d_out, int out_size, void* d_ws, size_t ws_size,
                              hipStream_t stream) {
  const float* inputs = (const float*)d_in[0];   // (B, 8) f32
  const float* weights = (const float*)d_in[1];  // (1, 45) f32
  float* out = (float*)d_out;                    // (B, 32) f32
  const int B = in_sizes[0] / 8;

  hipLaunchKernelGGL(qnn_main, dim3(B / 32), dim3(256), 0, stream,
                     inputs, weights, out);
}

// Round 9
// 19.362 us; speedup vs baseline: 1.9562x; 1.0455x over previous
//
#include <hip/hip_runtime.h>

typedef __fp16 h2 __attribute__((ext_vector_type(2)));
#define HALF_INV2PI 0.07957747154594766788f

// ---------------------------------------------------------------------------
// Packed f16 helpers. VOP3P f16 is FULL-rate (2 f16 FMA/lane/2cyc) vs
// half-rate pk_f32. op_sel/neg encodings identical to the verified f32 forms.
// Coefficients are computed per-lane in f32 and packed via v_cvt_pkrtz.
// ---------------------------------------------------------------------------
__device__ __forceinline__ h2 hpk(float lo, float hi) {
  return __builtin_amdgcn_cvt_pkrtz(lo, hi);
}
__device__ __forceinline__ h2 hsp(float a) {
  return __builtin_amdgcn_cvt_pkrtz(a, a);
}
__device__ __forceinline__ h2 hmul(h2 a, h2 b) {
  h2 d; asm("v_pk_mul_f16 %0, %1, %2" : "=v"(d) : "v"(a), "v"(b)); return d;
}
__device__ __forceinline__ h2 hfma(h2 a, h2 b, h2 c) {
  h2 d; asm("v_pk_fma_f16 %0, %1, %2, %3" : "=v"(d) : "v"(a), "v"(b), "v"(c));
  return d;
}
__device__ __forceinline__ h2 hfms(h2 a, h2 b, h2 c) {  // a*b - c
  h2 d; asm("v_pk_fma_f16 %0, %1, %2, %3 neg_lo:[0,0,1] neg_hi:[0,0,1]"
            : "=v"(d) : "v"(a), "v"(b), "v"(c));
  return d;
}
__device__ __forceinline__ h2 hfma_sw(h2 a, h2 b, h2 c) {  // a*swap(b) + c
  h2 d; asm("v_pk_fma_f16 %0, %1, %2, %3 op_sel:[0,1,0] op_sel_hi:[1,0,1]"
            : "=v"(d) : "v"(a), "v"(b), "v"(c));
  return d;
}
template<int CTRL>
__device__ __forceinline__ h2 hdpp(h2 v) {
  int x = __builtin_amdgcn_mov_dpp(__builtin_bit_cast(int, v), CTRL, 0xf, 0xf, true);
  return __builtin_bit_cast(h2, x);
}
__device__ __forceinline__ float hdot2(h2 a, h2 b, float c) {
#if __has_builtin(__builtin_amdgcn_fdot2)
  return __builtin_amdgcn_fdot2(a, b, c, false);
#else
  return __builtin_fmaf((float)a.y, (float)b.y,
         __builtin_fmaf((float)a.x, (float)b.x, c));
#endif
}

__device__ __forceinline__ void hw_sc(float rev, float& s, float& c) {
  s = __builtin_amdgcn_sinf(rev);
  c = __builtin_amdgcn_cosf(rev);
}

template<int J>
__device__ __forceinline__ float rl(float x) {
  return __int_as_float(__builtin_amdgcn_readlane(__float_as_int(x), J));
}
struct PC { float cB,sB,cA,sA,c0,s0,cd,sd,c4,s4; };
template<int J>
__device__ __forceinline__ PC loadpc(float cB,float sB,float cA,float sA,
                                     float c0,float s0,float cd,float sd,
                                     float c4,float s4) {
  PC c;
  c.cB=rl<J>(cB); c.sB=rl<J>(sB); c.cA=rl<J>(cA); c.sA=rl<J>(sA);
  c.c0=rl<J>(c0); c.s0=rl<J>(s0); c.cd=rl<J>(cd); c.sd=rl<J>(sd);
  c.c4=rl<J>(c4); c.s4=rl<J>(s4);
  return c;
}

// complex phase multiply on set s: R+iI *= (zr + i*zi), per-q1-component
#define CDIAG(s, zr, zi) do { \
    h2 _t  = hmul((zi), I[s]); \
    h2 _nR = hfms((zr), R[s], _t); \
    I[s] = hfma((zi), R[s], hmul((zr), I[s])); \
    R[s] = _nR; } while (0)

// ---------------------------------------------------------------------------
// Layout: 8 samples/wave (sample bits = lane{5,4,2}); per-lane 32 complex amps
//   in f16: set s = q0*8 + q2*4 + q4*2 + q7 (R[s],I[s] = h2), halves = q1.
//   Lane qubit bits: q3=bit3 (DPP row_ror:8), q6=bit1 (quad_perm [2,3,0,1]),
//   q5=bit0 (quad_perm [1,0,3,2]). Zero LDS/DS ops.
// ---------------------------------------------------------------------------
__global__ __launch_bounds__(256, 4) void qnn_main(const float* __restrict__ in,
                                                   const float* __restrict__ w,
                                                   float* __restrict__ out) {
  const int tid = threadIdx.x;
  const int wid = tid >> 6;
  const int lane = tid & 63;
  const int wv = blockIdx.x * 4 + wid;
  const int q3 = (lane >> 3) & 1, q6 = (lane >> 1) & 1, q5 = lane & 1;
  const int smp = ((lane >> 5) & 1) * 4 + ((lane >> 4) & 1) * 2 + ((lane >> 2) & 1);
  const float sgn3 = q3 ? 1.f : -1.f;
  const float sgn5 = q5 ? 1.f : -1.f;
  const float sgn6 = q6 ? 1.f : -1.f;

  // ---- in-kernel prep: lane j (j<9) computes pair j's 10 gate constants
  float gcB,gsB,gcA,gsA,gc0,gs0,gcd,gsd,gc4,gs4;
  {
    const int jj = (lane < 9) ? lane : 0;
    const float* wp = w + jj * 5;
    float w0 = wp[0], w1 = wp[1], w2 = wp[2], w3 = wp[3], w4 = wp[4];
    hw_sc(w0 * HALF_INV2PI, gsB, gcB);
    hw_sc((w0 + w1) * HALF_INV2PI, gsA, gcA);
    hw_sc((w2 + w3) * HALF_INV2PI, gs0, gc0);
    hw_sc((w2 - w3) * HALF_INV2PI, gsd, gcd);
    hw_sc(w4 * HALF_INV2PI, gs4, gc4);
  }
#define LOADPC(J) loadpc<J>(gcB,gsB,gcA,gsA,gc0,gs0,gcd,gsd,gc4,gs4)

  // ---- embedding: this lane's sample; product state, all real (f32)
  const float* ip = in + (wv * 8 + smp) * 8;
  float4 A4 = ((const float4*)ip)[0], B4 = ((const float4*)ip)[1];
  float xs[8] = {A4.x, A4.y, A4.z, A4.w, B4.x, B4.y, B4.z, B4.w};
  float vc[8], vs[8];
#pragma unroll
  for (int q = 0; q < 8; ++q)
    hw_sc(__builtin_fmaf(xs[q], HALF_INV2PI, 0.125f), vs[q], vc[q]);
  float prodL = (q3 ? vs[3] : vc[3]) * (q5 ? vs[5] : vc[5]) * (q6 ? vs[6] : vc[6]);
  float b[16];
  {
    float t0 = prodL * vc[0], t1 = prodL * vs[0];
    float u[4] = {t0 * vc[2], t0 * vs[2], t1 * vc[2], t1 * vs[2]};
    float z[8];
#pragma unroll
    for (int i = 0; i < 4; ++i) { z[i*2] = u[i]*vc[4]; z[i*2+1] = u[i]*vs[4]; }
#pragma unroll
    for (int i = 0; i < 8; ++i) { b[i*2] = z[i]*vc[7]; b[i*2+1] = z[i]*vs[7]; }
  }

  h2 R[16], I[16];

  // ---- G0 = D1_0(c=q0,t=q1) on real state;  B0: target q1 (op_sel swap)
  PC P0 = LOADPC(0);
  {
    h2 vq1p = hpk(vc[1], vs[1]);
    h2 mq1p = hpk(-vc[1], vs[1]);
    h2 Y0 = hpk(-P0.s0, P0.s0);
    h2 X1 = hpk(P0.sd, -P0.sd);
    h2 c0v = hsp(P0.c0), cdv = hsp(P0.cd);
#pragma unroll
    for (int s = 0; s < 16; ++s) {
      const bool Q0 = (s & 8) != 0;
      float br = b[s] * (Q0 ? P0.cA : P0.cB);
      float bi = b[s] * (Q0 ? P0.sA : P0.sB);
      h2 r = hmul(hsp(br), vq1p);
      h2 i = hmul(hsp(bi), mq1p);
      if (!Q0) {
        R[s] = hfma_sw(Y0, r, hmul(c0v, r));
        I[s] = hfma_sw(Y0, i, hmul(c0v, i));
      } else {
        R[s] = hfma_sw(cdv, r, hmul(X1, r));
        I[s] = hfma_sw(cdv, i, hmul(X1, i));
      }
    }
  }

  // ---- G1 = D3_0(c=q0,t=q1) * D1_1(c=q1,t=q2)
  PC P1 = LOADPC(1);
  {
    h2 zr1p = hpk(P1.cB, P1.cA);
    h2 zi1p[2] = { hpk(-P1.sB, -P1.sA), hpk(P1.sB, P1.sA) };
    h2 zrBp[2], ziBp[2];
#pragma unroll
    for (int t = 0; t < 2; ++t) {
      float eps = t ? 1.f : -1.f;
      float zix = eps * P1.sB, ziy = eps * P1.sA;
      float zrx = __builtin_fmaf(P0.s4, zix, P0.c4 * P1.cB);
      float zry = __builtin_fmaf(-P0.s4, ziy, P0.c4 * P1.cA);
      float zibx = __builtin_fmaf(-P0.s4, P1.cB, P0.c4 * zix);
      float ziby = __builtin_fmaf(P0.s4, P1.cA, P0.c4 * ziy);
      zrBp[t] = hpk(zrx, zry); ziBp[t] = hpk(zibx, ziby);
    }
#pragma unroll
    for (int s = 0; s < 16; ++s) {
      const int Q2 = (s >> 2) & 1;
      if (s & 8) { CDIAG(s, zrBp[Q2], ziBp[Q2]); }
      else       { CDIAG(s, zr1p, zi1p[Q2]); }
    }
  }
  // ---- B1: target q2 (register mix s<->s|4), control q1 (component vector)
  {
    h2 m00 = hpk(P1.c0, P1.sd), m01 = hpk(-P1.s0, P1.cd);
    h2 m10 = hpk(P1.s0, P1.cd), m11 = hpk(P1.c0, -P1.sd);
#pragma unroll
    for (int s = 0; s < 16; ++s) {
      if (s & 4) continue;
      const int a = s, c = s | 4;
      h2 t;
      t    = hfma(m01, R[c], hmul(m00, R[a]));
      R[c] = hfma(m11, R[c], hmul(m10, R[a])); R[a] = t;
      t    = hfma(m01, I[c], hmul(m00, I[a]));
      I[c] = hfma(m11, I[c], hmul(m10, I[a])); I[a] = t;
    }
  }

  // ---- G2 = D3_1(c=q1,t=q2) * D1_2(c=q2,t=q3)
  PC P2 = LOADPC(2);
  {
    float wr0 = P2.cB, wi0 = sgn3 * P2.sB;
    float wr1 = P2.cA, wi1 = sgn3 * P2.sA;
    h2 zrq[2] = { hpk(wr0, __builtin_fmaf(P1.s4, wi0, P1.c4*wr0)),
                  hpk(wr1, __builtin_fmaf(-P1.s4, wi1, P1.c4*wr1)) };
    h2 ziq[2] = { hpk(wi0, __builtin_fmaf(P1.c4, wi0, -P1.s4*wr0)),
                  hpk(wi1, __builtin_fmaf(P1.c4, wi1,  P1.s4*wr1)) };
#pragma unroll
    for (int s = 0; s < 16; ++s) {
      const int Q2 = (s >> 2) & 1;
      CDIAG(s, zrq[Q2], ziq[Q2]);
    }
  }
  // ---- B2: target q3 (DPP ror8), control q2 (set bit)
  {
    float Y0 = q3 ? P2.s0 : -P2.s0;
    float X1 = q3 ? -P2.sd : P2.sd;
    h2 Xv[2] = { hsp(P2.c0), hsp(X1) };
    h2 Yv[2] = { hsp(Y0), hsp(P2.cd) };
#pragma unroll
    for (int s = 0; s < 16; ++s) {
      const int Q2 = (s >> 2) & 1;
      h2 o = hdpp<0x128>(R[s]); R[s] = hfma(Yv[Q2], o, hmul(Xv[Q2], R[s]));
      o = hdpp<0x128>(I[s]);    I[s] = hfma(Yv[Q2], o, hmul(Xv[Q2], I[s]));
    }
  }

  // ---- G3 = D3_2(c=q2,t=q3) * D1_3(c=q3,t=q0)
  PC P3 = LOADPC(3);
  {
    float dr = q3 ? P3.cA : P3.cB;
    float di = q3 ? P3.sA : P3.sB;
    float ui = sgn3 * P2.s4;
    h2 z3r[2][2], z3i[2][2];  // [q2][q0]
    z3r[0][0] = hsp(dr);  z3i[0][0] = hsp(-di);
    z3r[0][1] = hsp(dr);  z3i[0][1] = hsp(di);
    z3r[1][0] = hsp(__builtin_fmaf(ui, di, P2.c4*dr));
    z3i[1][0] = hsp(__builtin_fmaf(ui, dr, -P2.c4*di));
    z3r[1][1] = hsp(__builtin_fmaf(-ui, di, P2.c4*dr));
    z3i[1][1] = hsp(__builtin_fmaf(ui, dr,  P2.c4*di));
#pragma unroll
    for (int s = 0; s < 16; ++s) {
      const int Q2 = (s >> 2) & 1, Q0 = (s >> 3) & 1;
      CDIAG(s, z3r[Q2][Q0], z3i[Q2][Q0]);
    }
  }
  // ---- B3: target q0 (register mix s<->s|8), control q3 (lane)
  {
    float m00 = q3 ? P3.sd : P3.c0, m01 = q3 ? P3.cd : -P3.s0;
    float m10 = q3 ? P3.cd : P3.s0, m11 = q3 ? -P3.sd : P3.c0;
    h2 M00 = hsp(m00), M01 = hsp(m01), M10 = hsp(m10), M11 = hsp(m11);
#pragma unroll
    for (int s = 0; s < 8; ++s) {
      const int a = s, c = s | 8;
      h2 t;
      t    = hfma(M01, R[c], hmul(M00, R[a]));
      R[c] = hfma(M11, R[c], hmul(M10, R[a])); R[a] = t;
      t    = hfma(M01, I[c], hmul(M00, I[a]));
      I[c] = hfma(M11, I[c], hmul(M10, I[a])); I[a] = t;
    }
  }

  // ---- G4 = D3_3(c=q3,t=q0) * D1_4(c=q3,t=q4)
  PC P4 = LOADPC(4);
  {
    float ar = q3 ? P3.c4 : 1.f, ai = q3 ? P3.s4 : 0.f;
    float wr = q3 ? P4.cA : P4.cB, wi = q3 ? P4.sA : P4.sB;
    float p = ar*wr, qq = ai*wi, r_ = ar*wi, t_ = ai*wr;
    h2 z4r[2][2] = {{hsp(p - qq), hsp(p + qq)}, {hsp(p + qq), hsp(p - qq)}};
    h2 z4i[2][2] = {{hsp(-r_ - t_), hsp(r_ - t_)}, {hsp(-r_ + t_), hsp(r_ + t_)}};
#pragma unroll
    for (int s = 0; s < 16; ++s) {
      const int Q0 = (s >> 3) & 1, Q4 = (s >> 1) & 1;
      CDIAG(s, z4r[Q0][Q4], z4i[Q0][Q4]);
    }
  }
  // ---- B4: target q4 (register mix s<->s|2), control q3 (lane)
  {
    float m00 = q3 ? P4.sd : P4.c0, m01 = q3 ? P4.cd : -P4.s0;
    float m10 = q3 ? P4.cd : P4.s0, m11 = q3 ? -P4.sd : P4.c0;
    h2 M00 = hsp(m00), M01 = hsp(m01), M10 = hsp(m10), M11 = hsp(m11);
#pragma unroll
    for (int s = 0; s < 16; ++s) {
      if (s & 2) continue;
      const int a = s, c = s | 2;
      h2 t;
      t    = hfma(M01, R[c], hmul(M00, R[a]));
      R[c] = hfma(M11, R[c], hmul(M10, R[a])); R[a] = t;
      t    = hfma(M01, I[c], hmul(M00, I[a]));
      I[c] = hfma(M11, I[c], hmul(M10, I[a])); I[a] = t;
    }
  }

  // ---- G5 = D3_4(c=q3,t=q4) * D1_5(c=q4,t=q5)
  PC P5 = LOADPC(5);
  {
    float ur = q3 ? P4.c4 : 1.f, ui = q3 ? P4.s4 : 0.f;
    float w0r = P5.cB, w0i = sgn5 * P5.sB;
    float w1r = P5.cA, w1i = sgn5 * P5.sA;
    h2 z5r[2] = { hsp(__builtin_fmaf(ui, w0i, ur*w0r)),
                  hsp(__builtin_fmaf(-ui, w1i, ur*w1r)) };
    h2 z5i[2] = { hsp(__builtin_fmaf(-ui, w0r, ur*w0i)),
                  hsp(__builtin_fmaf(ui, w1r, ur*w1i)) };
#pragma unroll
    for (int s = 0; s < 16; ++s) {
      const int Q4 = (s >> 1) & 1;
      CDIAG(s, z5r[Q4], z5i[Q4]);
    }
  }
  // ---- B5: target q5 (DPP quad_perm [1,0,3,2]), control q4 (set bit)
  {
    float Y0 = q5 ? P5.s0 : -P5.s0;
    float X1 = q5 ? -P5.sd : P5.sd;
    h2 Xv[2] = { hsp(P5.c0), hsp(X1) };
    h2 Yv[2] = { hsp(Y0), hsp(P5.cd) };
#pragma unroll
    for (int s = 0; s < 16; ++s) {
      const int Q4 = (s >> 1) & 1;
      h2 o = hdpp<0xB1>(R[s]); R[s] = hfma(Yv[Q4], o, hmul(Xv[Q4], R[s]));
      o = hdpp<0xB1>(I[s]);    I[s] = hfma(Yv[Q4], o, hmul(Xv[Q4], I[s]));
    }
  }

  // ---- G6 = D3_5(c=q4,t=q5) * D1_6(c=q5,t=q6)
  PC P6 = LOADPC(6);
  {
    float wr = q5 ? P6.cA : P6.cB;
    float wi = sgn6 * (q5 ? P6.sA : P6.sB);
    float vi = sgn5 * P5.s4;
    h2 z6r[2] = { hsp(wr), hsp(__builtin_fmaf(-vi, wi, P5.c4*wr)) };
    h2 z6i[2] = { hsp(wi), hsp(__builtin_fmaf(vi, wr, P5.c4*wi)) };
#pragma unroll
    for (int s = 0; s < 16; ++s) {
      const int Q4 = (s >> 1) & 1;
      CDIAG(s, z6r[Q4], z6i[Q4]);
    }
  }
  // ---- B6: target q6 (DPP quad_perm [2,3,0,1]), control q5 (lane)
  {
    float X = q5 ? (q6 ? -P6.sd : P6.sd) : P6.c0;
    float Y = q5 ? P6.cd : (q6 ? P6.s0 : -P6.s0);
    h2 Xv = hsp(X), Yv = hsp(Y);
#pragma unroll
    for (int s = 0; s < 16; ++s) {
      h2 o = hdpp<0x4E>(R[s]); R[s] = hfma(Yv, o, hmul(Xv, R[s]));
      o = hdpp<0x4E>(I[s]);    I[s] = hfma(Yv, o, hmul(Xv, I[s]));
    }
  }

  // ---- G7 = D3_6(c=q5,t=q6) * D1_7(c=q6,t=q7)
  PC P7 = LOADPC(7);
  {
    float ur = q5 ? P6.c4 : 1.f;
    float vi = sgn6 * (q5 ? P6.s4 : 0.f);
    float wr = q6 ? P7.cA : P7.cB, wi = q6 ? P7.sA : P7.sB;
    h2 z7r[2] = { hsp(__builtin_fmaf(vi, wi, ur*wr)),
                  hsp(__builtin_fmaf(-vi, wi, ur*wr)) };
    h2 z7i[2] = { hsp(__builtin_fmaf(vi, wr, -ur*wi)),
                  hsp(__builtin_fmaf(vi, wr, ur*wi)) };
#pragma unroll
    for (int s = 0; s < 16; ++s) {
      const int Q7 = s & 1;
      CDIAG(s, z7r[Q7], z7i[Q7]);
    }
  }
  // ---- B7: target q7 (register mix s<->s|1), control q6 (lane)
  {
    float m00 = q6 ? P7.sd : P7.c0, m01 = q6 ? P7.cd : -P7.s0;
    float m10 = q6 ? P7.cd : P7.s0, m11 = q6 ? -P7.sd : P7.c0;
    h2 M00 = hsp(m00), M01 = hsp(m01), M10 = hsp(m10), M11 = hsp(m11);
#pragma unroll
    for (int s = 0; s < 16; ++s) {
      if (s & 1) continue;
      const int a = s, c = s | 1;
      h2 t;
      t    = hfma(M01, R[c], hmul(M00, R[a]));
      R[c] = hfma(M11, R[c], hmul(M10, R[a])); R[a] = t;
      t    = hfma(M01, I[c], hmul(M00, I[a]));
      I[c] = hfma(M11, I[c], hmul(M10, I[a])); I[a] = t;
    }
  }

  // ---- G8 = D3_7(c=q6,t=q7) * D1_8(c=q7,t=q3)
  PC P8 = LOADPC(8);
  {
    float ur = q6 ? P7.c4 : 1.f, ui = q6 ? P7.s4 : 0.f;
    float w0r = P8.cB, w0i = sgn3 * P8.sB;
    float w1r = P8.cA, w1i = sgn3 * P8.sA;
    h2 z8r[2] = { hsp(__builtin_fmaf(ui, w0i, ur*w0r)),
                  hsp(__builtin_fmaf(-ui, w1i, ur*w1r)) };
    h2 z8i[2] = { hsp(__builtin_fmaf(-ui, w0r, ur*w0i)),
                  hsp(__builtin_fmaf(ui, w1r, ur*w1i)) };
#pragma unroll
    for (int s = 0; s < 16; ++s) {
      const int Q7 = s & 1;
      CDIAG(s, z8r[Q7], z8i[Q7]);
    }
  }
  // ---- B8: target q3 (DPP ror8), control q7 (set bit). Final D3 dropped.
  {
    float Y0 = q3 ? P8.s0 : -P8.s0;
    float X1 = q3 ? -P8.sd : P8.sd;
    h2 Xv[2] = { hsp(P8.c0), hsp(X1) };
    h2 Yv[2] = { hsp(Y0), hsp(P8.cd) };
#pragma unroll
    for (int s = 0; s < 16; ++s) {
      const int Q7 = s & 1;
      h2 o = hdpp<0x128>(R[s]); R[s] = hfma(Yv[Q7], o, hmul(Xv[Q7], R[s]));
      o = hdpp<0x128>(I[s]);    I[s] = hfma(Yv[Q7], o, hmul(Xv[Q7], I[s]));
    }
  }

  // ---- probs: marginalize q0,q2 (set bits), q1 (dot2 over halves), f32 acc
  float acc[4] = {0.f, 0.f, 0.f, 0.f};
#pragma unroll
  for (int s = 0; s < 16; ++s) {
    acc[s & 3] = hdot2(R[s], R[s], acc[s & 3]);
    acc[s & 3] = hdot2(I[s], I[s], acc[s & 3]);
  }
  // out index k = q3*16 + q4*8 + q5*4 + q6*2 + q7 ; acc[j]: j = q4*2 + q7
  const int k0 = q3 * 16 + q5 * 4 + q6 * 2;
  float* ob = out + (wv * 8 + smp) * 32 + k0;
  *(float2*)(ob) = make_float2(acc[0], acc[1]);
  *(float2*)(ob + 8) = make_float2(acc[2], acc[3]);
}

extern "C" void kernel_launch(void* const* d_in, const int* in_sizes, int n_in,
                              void* d_out, int out_size, void* d_ws, size_t ws_size,
                              hipStream_t stream) {
  const float* inputs = (const float*)d_in[0];   // (B, 8) f32
  const float* weights = (const float*)d_in[1];  // (1, 45) f32
  float* out = (float*)d_out;                    // (B, 32) f32
  const int B = in_sizes[0] / 8;

  hipLaunchKernelGGL(qnn_main, dim3(B / 32), dim3(256), 0, stream,
                     inputs, weights, out);
}